// Round 11
// baseline (469.033 us; speedup 1.0000x reference)
//
#include <hip/hip_runtime.h>
#include <hip/hip_bf16.h>

typedef __hip_bfloat16 bf16;
typedef unsigned short ush;
typedef short s16x8 __attribute__((ext_vector_type(8)));
typedef ush u16x4 __attribute__((ext_vector_type(4)));
typedef float f32x4 __attribute__((ext_vector_type(4)));

#define DEV __device__ __forceinline__

DEV float rcp_f(float x) { return __builtin_amdgcn_rcpf(x); }
DEV float sigmoid_f(float x) { return rcp_f(1.f + __expf(-x)); }
DEV float tanh_f(float x) { return 1.f - 2.f * rcp_f(__expf(2.f * x) + 1.f); }

DEV float u2f(ush u) { unsigned int v = ((unsigned int)u) << 16; float f; __builtin_memcpy(&f, &v, 4); return f; }
DEV ush f2u(float f) { bf16 h = __float2bfloat16(f); ush u; __builtin_memcpy(&u, &h, 2); return u; }

DEV f32x4 MFMA(s16x8 a, s16x8 b, f32x4 c) {
  return __builtin_amdgcn_mfma_f32_16x16x32_bf16(a, b, c, 0, 0, 0);
}

DEV s16x8 z8() {
  s16x8 v;
  for (int z = 0; z < 8; ++z) v[z] = 0;
  return v;
}

// swizzled element index within a [rows][32] bf16 chunk: 16B blocks XOR'd by (row>>1)&3
DEV int swz_idx(int row, int kk) { return row * 32 + (((kk >> 3) ^ ((row >> 1) & 3)) << 3) + (kk & 7); }
DEV int swz_blk(int row, int blk) { return row * 32 + ((blk ^ ((row >> 1) & 3)) << 3); }

// ---------------------------------------------------------------------------
// N=4096 graphs, K=8 nodes, n_in=14, H=128, k=3 iters. Inputs fp32.
// xh:  [32768][144] bf16 = [towers(14), pad(2), h(128)]
// FULL FUSION (gn_all, 512 blocks x 8 graphs, everything block-local):
//   enc (E_n MLP) -> e^0 (Ee MLP, LDS) -> [edge GRU -> node GRU] x3 -> sums
//   - edge state As_e stays in LDS the whole kernel (eh buffer DELETED)
//   - xh h-RAW is intra-block through __syncthreads (validated in R8)
//   - iteration loop is `#pragma unroll 1` (single body copy)
// R8's mega-fusion spilled because its pq_phase held a 384-float acc; pq is
// gone since R9 — peak acc here is 128 floats (same as R10's clean gn_iter).
// Edge GRU (transposed-C): D = WIHe·xx^T (9ck, r/z/n1) + WTh·e^T (4ck,
// r/z/n2); biases via biasM in the epilogue. Only edges (i,i+1) exist.
// ---------------------------------------------------------------------------

__global__ __launch_bounds__(256) void prep_all(
    const float* __restrict__ towers,
    const float* __restrict__ MWih, const float* __restrict__ MWhh,
    const float* __restrict__ UWih, const float* __restrict__ UWhh,
    const float* __restrict__ EnW1, const float* __restrict__ EnW2,
    const float* __restrict__ EeW1, const float* __restrict__ EeW2,
    const float* __restrict__ MBih, const float* __restrict__ MBhh,
    const float* __restrict__ UBih, const float* __restrict__ UBhh,
    const float* __restrict__ GWih, const float* __restrict__ GWhh,
    const float* __restrict__ GBih, const float* __restrict__ GBhh,
    ush* __restrict__ xh, ush* __restrict__ WIHe, ush* __restrict__ WTh,
    ush* __restrict__ WTu, ush* __restrict__ WBen1, ush* __restrict__ WBen2,
    ush* __restrict__ WBee1, ush* __restrict__ WBee2,
    float* __restrict__ biasM, float* __restrict__ biasU,
    float* __restrict__ WT_G, float* __restrict__ biasG)
{
  const int b = blockIdx.x, t = threadIdx.x;
  if (b < 2048) {                       // xh towers part: 32768*16
    const int idx = b * 256 + t;
    const int row = idx >> 4, kk = idx & 15;
    xh[row * 144 + kk] = f2u(kk < 14 ? towers[row * 14 + kk] : 0.f);
  } else if (b < 2480) {                // WIHe: 9*384*32 linear (edge Wih)
    const int idx = (b - 2048) * 256 + t;
    const int ck = idx / 12288, rem = idx % 12288, n = rem >> 5, kk = rem & 31;
    const int k = ck * 32 + kk;
    const int gate = n >> 7, c = n & 127;
    const int row = gate * 128 + c;
    int col = -1;
    if (k < 14)                    col = k;               // x_i
    else if (k >= 16 && k < 144)   col = 14 + (k - 16);   // h_i
    else if (k >= 144 && k < 158)  col = 142 + (k - 144); // x_j
    else if (k >= 160)             col = 156 + (k - 160); // h_j
    WIHe[idx] = f2u((col >= 0) ? MWih[row * 284 + col] : 0.f);
  } else if (b < 2672) {                // WTh: 4*384*32 linear
    const int idx = (b - 2480) * 256 + t;
    const int ck = idx / 12288, rem = idx % 12288, n = rem >> 5, kk = rem & 31;
    const int g = n >> 7, c = n & 127;
    WTh[idx] = f2u(MWhh[(g * 128 + c) * 128 + ck * 32 + kk]);
  } else if (b < 3248) {                // WTu: 9*512*32 swizzled
    const int idx = (b - 2672) * 256 + t;
    const int ck = idx >> 14, n = (idx >> 5) & 511, kk = idx & 31;
    const int k = ck * 32 + kk, gate = n >> 7, c = n & 127;
    float w = 0.f;
    const int row = (gate == 0) ? c : (gate == 1) ? 128 + c : 256 + c;
    if (k < 160) {
      int col = -1;
      if (k < 16)        { if (k < 14) col = k; }
      else if (k < 144)  col = 14 + (k - 16);
      if (gate != 3 && col >= 0) w = UWih[row * 142 + col];
    } else {
      if (gate != 2) w = UWhh[row * 128 + (k - 160)];
    }
    WTu[ck * 16384 + swz_idx(n, kk)] = f2u(w);
  } else if (b < 3264) {                // WBen1: 128x32 linear
    const int idx = (b - 3248) * 256 + t;
    const int n = (idx >> 5) & 127, kk = idx & 31;
    WBen1[idx] = f2u(kk < 14 ? EnW1[n * 14 + kk] : 0.f);
  } else if (b < 3328) {                // WBen2: 4*128*32 linear
    const int idx = (b - 3264) * 256 + t;
    const int ck = idx >> 12, n = (idx >> 5) & 127, kk = idx & 31;
    WBen2[idx] = f2u(EnW2[n * 128 + ck * 32 + kk]);
  } else if (b < 3344) {                // WBee1: 128x32 pair linear
    const int idx = (b - 3328) * 256 + t;
    const int n = (idx >> 5) & 127, kk = idx & 31;
    int col = (kk < 16) ? (kk < 14 ? kk : -1) : (kk < 30 ? 14 + (kk - 16) : -1);
    WBee1[idx] = f2u(col >= 0 ? EeW1[n * 28 + col] : 0.f);
    (void)n;
  } else if (b < 3408) {                // WBee2: 4*128*32 linear
    const int idx = (b - 3344) * 256 + t;
    const int ck = idx >> 12, n = (idx >> 5) & 127, kk = idx & 31;
    WBee2[idx] = f2u(EeW2[n * 128 + ck * 32 + kk]);
  } else if (b < 3410) {                // biasM [4 gates][128]
    const int idx = (b - 3408) * 256 + t;
    const int g = idx >> 7, c = idx & 127;
    float v;
    if (g == 0)      v = MBih[c] + MBhh[c];
    else if (g == 1) v = MBih[128 + c] + MBhh[128 + c];
    else if (g == 2) v = MBih[256 + c];
    else             v = MBhh[256 + c];
    biasM[idx] = v;
  } else if (b < 3412) {                // biasU
    const int idx = (b - 3410) * 256 + t;
    const int g = idx >> 7, c = idx & 127;
    float v;
    if (g == 0)      v = UBih[c] + UBhh[c];
    else if (g == 1) v = UBih[128 + c] + UBhh[128 + c];
    else if (g == 2) v = UBih[256 + c];
    else             v = UBhh[256 + c];
    biasU[idx] = v;
  } else if (b < 4180) {                // WT_G interleaved fp32: 384*512
    const int idx = (b - 3412) * 256 + t;
    const int kc = idx >> 9, cg = (idx >> 2) & 127, gate = idx & 3;
    const int row = (gate == 0) ? cg : (gate == 1) ? cg + 128 : cg + 256;
    float v = 0.f;
    if (kc < 256) { if (gate != 3) v = GWih[row * 256 + kc]; }
    else          { if (gate != 2) v = GWhh[row * 128 + (kc - 256)]; }
    WT_G[idx] = v;
  } else {                              // biasG
    const int idx = (b - 4180) * 256 + t;
    const int cg = idx >> 2, gate = idx & 3;
    float v;
    if (gate == 0)      v = GBih[cg] + GBhh[cg];
    else if (gate == 1) v = GBih[cg + 128] + GBhh[cg + 128];
    else if (gate == 2) v = GBih[cg + 256];
    else                v = GBhh[cg + 256];
    biasG[idx] = v;
  }
}

// ---------------------------------------------------------------------------
// 2-layer tanh MLP (shared shape of E_n and E_e): A1 staged by caller into
// SC[0,1024), output written via `put(r, col, val)`.
// ---------------------------------------------------------------------------
template<class PUT>
DEV void mlp2_body(ush* SC, const ush* __restrict__ WB1, const float* __restrict__ b1,
                   const ush* __restrict__ WB2, const float* __restrict__ b2,
                   int t, PUT&& put)
{
  ush* A1 = SC;
  ush* Z1 = SC + 1024;
  const int lane = t & 63, w = t >> 6;
  const int quad = lane >> 4, l15 = lane & 15;

  // layer 1 (K=32)
  s16x8 af[4];
  #pragma unroll
  for (int rt = 0; rt < 4; ++rt)
    af[rt] = *(const s16x8*)&A1[swz_blk(rt * 16 + l15, quad)];
  f32x4 acc1[4][2];
  #pragma unroll
  for (int rt = 0; rt < 4; ++rt)
    #pragma unroll
    for (int ct = 0; ct < 2; ++ct) {
      #pragma unroll
      for (int q = 0; q < 4; ++q) acc1[rt][ct][q] = 0.f;
    }
  #pragma unroll
  for (int ct = 0; ct < 2; ++ct) {
    const int n = w * 32 + ct * 16 + l15;
    const s16x8 bf = *(const s16x8*)&WB1[n * 32 + quad * 8];
    #pragma unroll
    for (int rt = 0; rt < 4; ++rt) acc1[rt][ct] = MFMA(af[rt], bf, acc1[rt][ct]);
  }
  #pragma unroll
  for (int ct = 0; ct < 2; ++ct) {
    const int col = w * 32 + ct * 16 + l15;
    const int kk = col & 31;
    #pragma unroll
    for (int rt = 0; rt < 4; ++rt) {
      #pragma unroll
      for (int q = 0; q < 4; ++q) {
        const int m = rt * 16 + quad * 4 + q;
        Z1[w * 2048 + swz_idx(m, kk)] = f2u(tanh_f(acc1[rt][ct][q] + b1[col]));
      }
    }
  }
  __syncthreads();

  // layer 2 (K=128)
  f32x4 acc2[4][2];
  #pragma unroll
  for (int rt = 0; rt < 4; ++rt)
    #pragma unroll
    for (int ct = 0; ct < 2; ++ct) {
      #pragma unroll
      for (int q = 0; q < 4; ++q) acc2[rt][ct][q] = 0.f;
    }
  for (int ck2 = 0; ck2 < 4; ++ck2) {
    #pragma unroll
    for (int rt = 0; rt < 4; ++rt)
      af[rt] = *(const s16x8*)&Z1[ck2 * 2048 + swz_blk(rt * 16 + l15, quad)];
    #pragma unroll
    for (int ct = 0; ct < 2; ++ct) {
      const int n = w * 32 + ct * 16 + l15;
      const s16x8 bf = *(const s16x8*)&WB2[(ck2 * 128 + n) * 32 + quad * 8];
      #pragma unroll
      for (int rt = 0; rt < 4; ++rt) acc2[rt][ct] = MFMA(af[rt], bf, acc2[rt][ct]);
    }
  }
  #pragma unroll
  for (int ct = 0; ct < 2; ++ct) {
    const int col = w * 32 + ct * 16 + l15;
    #pragma unroll
    for (int rt = 0; rt < 4; ++rt) {
      #pragma unroll
      for (int q = 0; q < 4; ++q) {
        const int r = rt * 16 + quad * 4 + q;
        put(r, col, tanh_f(acc2[rt][ct][q] + b2[col]));
      }
    }
  }
}

// ---------------------------------------------------------------------------
// Edge GRU core: D = WIHe·xx^T (9 ck) + WTh·e^T (4 ck); As_e updated in
// place (barrier separates h-phase reads from the in-place write).
// ---------------------------------------------------------------------------
DEV void edge_core(ush* As_e, ush* Bxx,
                   const ush* __restrict__ WIHe, const ush* __restrict__ WTh,
                   const float* __restrict__ biasM,
                   const ush* __restrict__ xh, int G0, int t)
{
  const int lane = t & 63, w = t >> 6;
  const int quad = lane >> 4, l15 = lane & 15;
  const int ko = quad * 8;

  f32x4 accR[2][4], accZ[2][4], accN1[2][4], accN2[2][4];
  #pragma unroll
  for (int mt = 0; mt < 2; ++mt)
    #pragma unroll
    for (int nt = 0; nt < 4; ++nt) {
      #pragma unroll
      for (int q = 0; q < 4; ++q) { accR[mt][nt][q] = 0.f; accZ[mt][nt][q] = 0.f; accN1[mt][nt][q] = 0.f; accN2[mt][nt][q] = 0.f; }
    }

  auto stage_xx = [&](int ck) {
    const int gm = t >> 2, gb = t & 3;
    const int gg = gm >> 3, i = gm & 7;
    const int xi = (G0 + gg) * 8 + i;
    const int xj = xi + ((i < 7) ? 1 : 0);
    const int k0 = ck * 32 + gb * 8;
    const s16x8 v = (k0 < 144) ? *(const s16x8*)(xh + xi * 144 + k0)
                               : *(const s16x8*)(xh + xj * 144 + (k0 - 144));
    *(s16x8*)&Bxx[(ck & 1) * 2048 + swz_blk(gm, gb)] = v;
  };

  // xx phase: K = 288 (9 chunks), gates r, z, n1
  stage_xx(0);
  __syncthreads();
  for (int ck = 0; ck < 9; ++ck) {
    if (ck + 1 < 9) stage_xx(ck + 1);
    const ush* Bc = Bxx + (ck & 1) * 2048;
    s16x8 be[4];
    #pragma unroll
    for (int nt = 0; nt < 4; ++nt)
      be[nt] = *(const s16x8*)&Bc[swz_blk(nt * 16 + l15, quad)];
    #pragma unroll
    for (int mt = 0; mt < 2; ++mt) {
      const int nb = w * 32 + mt * 16 + l15;
      const s16x8 aR = *(const s16x8*)&WIHe[(ck * 384 + nb) * 32 + ko];
      const s16x8 aZ = *(const s16x8*)&WIHe[(ck * 384 + 128 + nb) * 32 + ko];
      const s16x8 aN = *(const s16x8*)&WIHe[(ck * 384 + 256 + nb) * 32 + ko];
      #pragma unroll
      for (int nt = 0; nt < 4; ++nt) {
        accR[mt][nt]  = MFMA(aR, be[nt], accR[mt][nt]);
        accZ[mt][nt]  = MFMA(aZ, be[nt], accZ[mt][nt]);
        accN1[mt][nt] = MFMA(aN, be[nt], accN1[mt][nt]);
      }
    }
    __syncthreads();
  }

  // h phase: K = 128 (4 chunks) from As_e, gates r, z, n2
  #pragma unroll
  for (int ck = 0; ck < 4; ++ck) {
    s16x8 be[4];
    #pragma unroll
    for (int nt = 0; nt < 4; ++nt)
      be[nt] = *(const s16x8*)&As_e[ck * 2048 + swz_blk(nt * 16 + l15, quad)];
    #pragma unroll
    for (int mt = 0; mt < 2; ++mt) {
      const int nb = w * 32 + mt * 16 + l15;
      const s16x8 aR = *(const s16x8*)&WTh[(ck * 384 + nb) * 32 + ko];
      const s16x8 aZ = *(const s16x8*)&WTh[(ck * 384 + 128 + nb) * 32 + ko];
      const s16x8 aN = *(const s16x8*)&WTh[(ck * 384 + 256 + nb) * 32 + ko];
      #pragma unroll
      for (int nt = 0; nt < 4; ++nt) {
        accR[mt][nt]  = MFMA(aR, be[nt], accR[mt][nt]);
        accZ[mt][nt]  = MFMA(aZ, be[nt], accZ[mt][nt]);
        accN2[mt][nt] = MFMA(aN, be[nt], accN2[mt][nt]);
      }
    }
  }

  __syncthreads();   // all h-phase As_e reads complete before in-place update

  // epilogue: biases + GRU; in-place As_e update (1:1 thread ownership)
  #pragma unroll
  for (int mt = 0; mt < 2; ++mt) {
    const int hc0 = w * 32 + mt * 16 + quad * 4;
    const int ck2 = hc0 >> 5, kkB = hc0 & 31;
    #pragma unroll
    for (int nt = 0; nt < 4; ++nt) {
      const int erow = nt * 16 + l15;
      ush* cell = &As_e[ck2 * 2048 + swz_blk(erow, kkB >> 3) + (kkB & 7)];
      const u16x4 hp4 = *(const u16x4*)cell;
      u16x4 ov;
      #pragma unroll
      for (int q = 0; q < 4; ++q) {
        const int c = hc0 + q;
        const float rg = sigmoid_f(accR[mt][nt][q] + biasM[c]);
        const float zg = sigmoid_f(accZ[mt][nt][q] + biasM[128 + c]);
        const float nn = tanh_f(accN1[mt][nt][q] + biasM[256 + c]
                                + rg * (accN2[mt][nt][q] + biasM[384 + c]));
        const float hp = u2f(hp4[q]);
        ov[q] = f2u(nn + zg * (hp - nn));
      }
      *(u16x4*)cell = ov;
    }
  }
}

// ---------------------------------------------------------------------------
// Node GRU reading edges from As_e (LDS): WTu B direct-global, dbuf staging.
// ---------------------------------------------------------------------------
DEV void node_lds(const ush* As_e, ush* SC, ush* __restrict__ xh,
                  const ush* __restrict__ WT, const float* __restrict__ bias,
                  int rowBase, int t)
{
  constexpr int NCH = 9, XCH = 5;
  const int lane = t & 63, w = t >> 6;
  const int gm = t >> 2, gb = t & 3, grow = rowBase + gm;
  const int l15 = lane & 15, quad = lane >> 4;

  f32x4 accR[4][2], accZ[4][2], accN1[4][2], accN2[4][2];
  #pragma unroll
  for (int rt = 0; rt < 4; ++rt)
    #pragma unroll
    for (int s = 0; s < 2; ++s) {
      #pragma unroll
      for (int q = 0; q < 4; ++q) { accR[rt][s][q] = 0.f; accZ[rt][s][q] = 0.f; accN1[rt][s][q] = 0.f; accN2[rt][s][q] = 0.f; }
    }

  auto stage = [&](int ck) {
    const int k0 = ck * 32 + gb * 8;
    s16x8 v = z8();
    if (k0 < 16)       v = *(const s16x8*)(xh + grow * 144 + k0);
    else if (k0 < 144) {
      const int i = gm & 7;
      if (i < 7) {
        const int ke = k0 - 16;
        v = *(const s16x8*)&As_e[(ke >> 5) * 2048 + swz_blk(gm, (ke & 31) >> 3)];
      }
    } else if (k0 >= 160) {
      v = *(const s16x8*)(xh + grow * 144 + 16 + (k0 - 160));
    }
    *(s16x8*)&SC[(ck & 1) * 2048 + swz_blk(gm, gb)] = v;
  };

  stage(0);
  __syncthreads();

  for (int ck = 0; ck < NCH; ++ck) {
    if (ck + 1 < NCH) stage(ck + 1);

    const ush* Wc = WT + ck * 16384;
    const ush* Ac = SC + (ck & 1) * 2048;
    s16x8 af[4];
    #pragma unroll
    for (int rt = 0; rt < 4; ++rt)
      af[rt] = *(const s16x8*)&Ac[swz_blk(rt * 16 + l15, quad)];
    if (ck < XCH) {
      #pragma unroll
      for (int s = 0; s < 2; ++s) {
        const int nb = w * 32 + s * 16 + l15;
        const s16x8 bR = *(const s16x8*)&Wc[swz_blk(0 * 128 + nb, quad)];
        const s16x8 bZ = *(const s16x8*)&Wc[swz_blk(1 * 128 + nb, quad)];
        const s16x8 bN = *(const s16x8*)&Wc[swz_blk(2 * 128 + nb, quad)];
        #pragma unroll
        for (int rt = 0; rt < 4; ++rt) {
          accR[rt][s]  = MFMA(af[rt], bR, accR[rt][s]);
          accZ[rt][s]  = MFMA(af[rt], bZ, accZ[rt][s]);
          accN1[rt][s] = MFMA(af[rt], bN, accN1[rt][s]);
        }
      }
    } else {
      #pragma unroll
      for (int s = 0; s < 2; ++s) {
        const int nb = w * 32 + s * 16 + l15;
        const s16x8 bR = *(const s16x8*)&Wc[swz_blk(0 * 128 + nb, quad)];
        const s16x8 bZ = *(const s16x8*)&Wc[swz_blk(1 * 128 + nb, quad)];
        const s16x8 bN = *(const s16x8*)&Wc[swz_blk(3 * 128 + nb, quad)];
        #pragma unroll
        for (int rt = 0; rt < 4; ++rt) {
          accR[rt][s]  = MFMA(af[rt], bR, accR[rt][s]);
          accZ[rt][s]  = MFMA(af[rt], bZ, accZ[rt][s]);
          accN2[rt][s] = MFMA(af[rt], bN, accN2[rt][s]);
        }
      }
    }
    __syncthreads();
  }

  #pragma unroll
  for (int s = 0; s < 2; ++s) {
    const int hcol = w * 32 + s * 16 + l15;
    const float bR = bias[hcol], bZ = bias[128 + hcol], bN1 = bias[256 + hcol], bN2 = bias[384 + hcol];
    #pragma unroll
    for (int rt = 0; rt < 4; ++rt) {
      #pragma unroll
      for (int q = 0; q < 4; ++q) {
        const int r = rt * 16 + quad * 4 + q;
        const int row = rowBase + r;
        const float hp = u2f(xh[row * 144 + 16 + hcol]);
        const float rg = sigmoid_f(accR[rt][s][q] + bR);
        const float zg = sigmoid_f(accZ[rt][s][q] + bZ);
        const float nn = tanh_f(accN1[rt][s][q] + bN1 + rg * (accN2[rt][s][q] + bN2));
        xh[row * 144 + 16 + hcol] = f2u(nn + zg * (hp - nn));
      }
    }
  }
}

// per-block readout: esum from As_e (final edges), hsum from xh (final h)
DEV void sums_body(const ush* As_e, const ush* __restrict__ xh,
                   float* __restrict__ hsum, float* __restrict__ esum,
                   int G0, int rowBase, int t)
{
  #pragma unroll
  for (int ii = 0; ii < 4; ++ii) {
    const int p = t + ii * 256;
    const int gg = p >> 7, hh = p & 127;
    float es = 0.f;
    #pragma unroll
    for (int i = 0; i < 7; ++i) {
      const int slot = gg * 8 + i;
      es += u2f(As_e[(hh >> 5) * 2048 + swz_idx(slot, hh & 31)]);
    }
    float hs = 0.f;
    #pragma unroll
    for (int i = 0; i < 8; ++i)
      hs += u2f(xh[(rowBase + gg * 8 + i) * 144 + 16 + hh]);
    hsum[(G0 + gg) * 128 + hh] = hs;
    esum[(G0 + gg) * 128 + hh] = es;
  }
}

// ---------------------------------------------------------------------------
// The fully fused GN: enc -> e^0 -> (edge -> node) x3 -> sums. 512 blocks.
// ---------------------------------------------------------------------------
__global__ __launch_bounds__(256, 2) void gn_all(
    ush* __restrict__ xh,
    const ush* __restrict__ WBen1, const float* __restrict__ bEn1,
    const ush* __restrict__ WBen2, const float* __restrict__ bEn2,
    const ush* __restrict__ WBee1, const float* __restrict__ bEe1,
    const ush* __restrict__ WBee2, const float* __restrict__ bEe2,
    const ush* __restrict__ WIHe, const ush* __restrict__ WTh,
    const float* __restrict__ biasM,
    const ush* __restrict__ WTu, const float* __restrict__ biasU,
    float* __restrict__ hsum, float* __restrict__ esum)
{
  __shared__ ush smem[17408];          // As_e [0,8192) | SC [8192,17408)
  ush* As_e = smem;
  ush* SC   = smem + 8192;
  const int t = threadIdx.x;
  const int G0 = blockIdx.x * 8, rowBase = blockIdx.x * 64;

  // --- enc: E_n MLP, 64 node rows -> h into xh ---
  {
    const int gm = t >> 2, gb = t & 3, grow = rowBase + gm;
    s16x8 v = z8();
    if (gb < 2) v = *(const s16x8*)(xh + grow * 144 + gb * 8);
    *(s16x8*)&SC[swz_blk(gm, gb)] = v;
  }
  __syncthreads();
  mlp2_body(SC, WBen1, bEn1, WBen2, bEn2, t,
            [&](int r, int col, float v) {
              xh[(rowBase + r) * 144 + 16 + col] = f2u(v);
            });
  __syncthreads();

  // --- e^0: Ee MLP on the (i,i+1) pairs -> As_e ---
  {
    const int gm = t >> 2, gb = t & 3;
    const int gg = gm >> 3, i = gm & 7;
    const int xi = (G0 + gg) * 8 + i;
    const int xj = (i < 7) ? xi + 1 : xi;
    const s16x8 v = (gb < 2) ? *(const s16x8*)(xh + xi * 144 + gb * 8)
                             : *(const s16x8*)(xh + xj * 144 + (gb - 2) * 8);
    *(s16x8*)&SC[swz_blk(gm, gb)] = v;
  }
  __syncthreads();
  mlp2_body(SC, WBee1, bEe1, WBee2, bEe2, t,
            [&](int r, int col, float v) {
              As_e[(col >> 5) * 2048 + swz_idx(r, col & 31)] = f2u(v);
            });
  __syncthreads();

  // --- k = 3 GN iterations, edge state resident in LDS ---
  #pragma unroll 1
  for (int it = 0; it < 3; ++it) {
    edge_core(As_e, SC, WIHe, WTh, biasM, xh, G0, t);
    __syncthreads();
    node_lds(As_e, SC, xh, WTu, biasU, rowBase, t);
    __syncthreads();
  }

  sums_body(As_e, xh, hsum, esum, G0, rowBase, t);
}

// global GRU (h_prev = 0) fused with output head: 16 graphs per block.
__global__ __launch_bounds__(256) void gru_global_out(
    const float* __restrict__ hsum, const float* __restrict__ esum,
    const float* __restrict__ WT, const float* __restrict__ bias,
    const float* __restrict__ OW, const float* __restrict__ Ob,
    float* __restrict__ out)
{
  constexpr int KT = 384;
  __shared__ float4 ATl4[KT * 4];
  __shared__ float4 Bl4[16 * 128];
  __shared__ float gmat[16 * 128];
  __shared__ float red[16 * 4];
  float* ATl = (float*)ATl4;
  const int t = threadIdx.x;
  const int rowBase = blockIdx.x * 16;
  for (int idx = t; idx < KT * 16; idx += 256) {
    const int kc = idx >> 4, r = idx & 15, grow = rowBase + r;
    float v = 0.f;
    if (kc < 128)      v = hsum[grow * 128 + kc];
    else if (kc < 256) v = esum[grow * 128 + (kc - 128)];
    ATl[idx] = v;
  }
  const int c = t & 127, rh = t >> 7;
  float accR[8], accZ[8], accN1[8];
  #pragma unroll
  for (int rr = 0; rr < 8; ++rr) { accR[rr] = 0.f; accZ[rr] = 0.f; accN1[rr] = 0.f; }
  const float4* WT4 = (const float4*)WT;
  for (int ck = 0; ck < 16; ++ck) {
    __syncthreads();
    #pragma unroll
    for (int ii = 0; ii < 8; ++ii) { const int idx = t + ii * 256; Bl4[idx] = WT4[ck * 2048 + idx]; }
    __syncthreads();
    const int kb = ck * 16;
    #pragma unroll
    for (int kcl = 0; kcl < 16; ++kcl) {
      const float4 wv = Bl4[kcl * 128 + c];
      const float4 a0 = ATl4[(kb + kcl) * 4 + rh * 2];
      const float4 a1 = ATl4[(kb + kcl) * 4 + rh * 2 + 1];
      const float av[8] = {a0.x, a0.y, a0.z, a0.w, a1.x, a1.y, a1.z, a1.w};
      #pragma unroll
      for (int rr = 0; rr < 8; ++rr) {
        accR[rr]  += wv.x * av[rr];
        accZ[rr]  += wv.y * av[rr];
        accN1[rr] += wv.z * av[rr];
      }
    }
  }
  const float4 bb = ((const float4*)bias)[c];
  const float ow = OW[c];
  #pragma unroll
  for (int rr = 0; rr < 8; ++rr) {
    const float rg = sigmoid_f(accR[rr] + bb.x);
    const float zg = sigmoid_f(accZ[rr] + bb.y);
    const float nn = tanh_f(accN1[rr] + bb.z + rg * bb.w);
    gmat[(rh * 8 + rr) * 128 + c] = (1.f - zg) * nn * ow;
  }
  __syncthreads();
  if (t < 64) {
    const int r = t >> 2, part = t & 3;
    float s = 0.f;
    #pragma unroll
    for (int cc = 0; cc < 32; ++cc) s += gmat[r * 128 + part * 32 + cc];
    red[r * 4 + part] = s;
  }
  __syncthreads();
  if (t < 16) {
    const float s = red[t * 4] + red[t * 4 + 1] + red[t * 4 + 2] + red[t * 4 + 3];
    out[rowBase + t] = sigmoid_f(s + Ob[0]);
  }
}

// ---------------------------------------------------------------------------
extern "C" void kernel_launch(void* const* d_in, const int* in_sizes, int n_in,
                              void* d_out, int out_size, void* d_ws, size_t ws_size,
                              hipStream_t stream)
{
  (void)in_sizes; (void)n_in; (void)out_size; (void)ws_size;
  const float* towers = (const float*)d_in[0];
  const float* EnW1 = (const float*)d_in[1];
  const float* EnB1 = (const float*)d_in[2];
  const float* EnW2 = (const float*)d_in[3];
  const float* EnB2 = (const float*)d_in[4];
  const float* EeW1 = (const float*)d_in[5];
  const float* EeB1 = (const float*)d_in[6];
  const float* EeW2 = (const float*)d_in[7];
  const float* EeB2 = (const float*)d_in[8];
  const float* UWih = (const float*)d_in[9];
  const float* UWhh = (const float*)d_in[10];
  const float* UBih = (const float*)d_in[11];
  const float* UBhh = (const float*)d_in[12];
  const float* MWih = (const float*)d_in[13];
  const float* MWhh = (const float*)d_in[14];
  const float* MBih = (const float*)d_in[15];
  const float* MBhh = (const float*)d_in[16];
  const float* GWih = (const float*)d_in[17];
  const float* GWhh = (const float*)d_in[18];
  const float* GBih = (const float*)d_in[19];
  const float* GBhh = (const float*)d_in[20];
  const float* OW   = (const float*)d_in[21];
  const float* Ob   = (const float*)d_in[22];

  char* ws = (char*)d_ws;
  size_t off = 0;
  auto take = [&](size_t b) { void* p = ws + off; off = (off + b + 255) & ~(size_t)255; return p; };
  ush*   xh     = (ush*)take((size_t)32768 * 144 * 2);
  float* hsum   = (float*)take((size_t)4096 * 128 * 4);
  float* esum   = (float*)take((size_t)4096 * 128 * 4);
  ush*   WIHe   = (ush*)take((size_t)9 * 384 * 32 * 2);
  ush*   WTh    = (ush*)take((size_t)4 * 384 * 32 * 2);
  ush*   WTu    = (ush*)take((size_t)9 * 512 * 32 * 2);
  ush*   WBen1  = (ush*)take((size_t)128 * 32 * 2);
  ush*   WBen2  = (ush*)take((size_t)4 * 128 * 32 * 2);
  ush*   WBee1  = (ush*)take((size_t)128 * 32 * 2);
  ush*   WBee2  = (ush*)take((size_t)4 * 128 * 32 * 2);
  float* biasM  = (float*)take(512 * 4);
  float* biasU  = (float*)take(512 * 4);
  float* WT_G   = (float*)take((size_t)384 * 512 * 4);
  float* biasG  = (float*)take(512 * 4);

  prep_all<<<4182, 256, 0, stream>>>(
      towers, MWih, MWhh, UWih, UWhh, EnW1, EnW2, EeW1, EeW2,
      MBih, MBhh, UBih, UBhh, GWih, GWhh, GBih, GBhh,
      xh, WIHe, WTh, WTu, WBen1, WBen2, WBee1, WBee2,
      biasM, biasU, WT_G, biasG);

  gn_all<<<512, 256, 0, stream>>>(
      xh, WBen1, EnB1, WBen2, EnB2, WBee1, EeB1, WBee2, EeB2,
      WIHe, WTh, biasM, WTu, biasU, hsum, esum);

  gru_global_out<<<256, 256, 0, stream>>>(hsum, esum, WT_G, biasG, OW, Ob, (float*)d_out);
}

// Round 12
// 284.461 us; speedup vs baseline: 1.6488x; 1.6488x over previous
//
#include <hip/hip_runtime.h>
#include <hip/hip_bf16.h>

typedef __hip_bfloat16 bf16;
typedef unsigned short ush;
typedef short s16x8 __attribute__((ext_vector_type(8)));
typedef ush u16x4 __attribute__((ext_vector_type(4)));
typedef float f32x4 __attribute__((ext_vector_type(4)));

#define DEV __device__ __forceinline__

DEV float rcp_f(float x) { return __builtin_amdgcn_rcpf(x); }
DEV float sigmoid_f(float x) { return rcp_f(1.f + __expf(-x)); }
DEV float tanh_f(float x) { return 1.f - 2.f * rcp_f(__expf(2.f * x) + 1.f); }

DEV float u2f(ush u) { unsigned int v = ((unsigned int)u) << 16; float f; __builtin_memcpy(&f, &v, 4); return f; }
DEV ush f2u(float f) { bf16 h = __float2bfloat16(f); ush u; __builtin_memcpy(&u, &h, 2); return u; }

DEV f32x4 MFMA(s16x8 a, s16x8 b, f32x4 c) {
  return __builtin_amdgcn_mfma_f32_16x16x32_bf16(a, b, c, 0, 0, 0);
}

DEV s16x8 z8() {
  s16x8 v;
  for (int z = 0; z < 8; ++z) v[z] = 0;
  return v;
}

// swizzled element index within a [rows][32] bf16 chunk: 16B blocks XOR'd by (row>>1)&3
DEV int swz_idx(int row, int kk) { return row * 32 + (((kk >> 3) ^ ((row >> 1) & 3)) << 3) + (kk & 7); }
DEV int swz_blk(int row, int blk) { return row * 32 + ((blk ^ ((row >> 1) & 3)) << 3); }

// ---------------------------------------------------------------------------
// N=4096 graphs, K=8 nodes, n_in=14, H=128, k=3 iters. Inputs fp32.
// xh:  [32768][144] bf16 = [towers(14), pad(2), h(128)]
// eh:  iteration-carry only (rows g*64 + i*9+1).
// PER-ITERATION FUSION, HALF BLOCKS (gn_iter<FIRST,LAST>, 1024 blocks x
// 4 graphs / 32 rows — R10 used 8 graphs): acc tiles 64 floats (was 128) ->
// ~3 blocks/CU resident instead of 2, more independent barrier chains per
// CU (the R10 profile was latency-bound: MfmaUtil 15%, occ 15.7%).
//   [FIRST: Ee MLP -> As_e] / [else: load As_e from eh]
//   edge GRU (WIHe·xx^T 9ck + WTh·e^T 4ck) -> As_e in place (+eh if !LAST)
//   node GRU reads edges from As_e (LDS)
//   [LAST: per-block hsum/esum]
// Fusion law (R8/R11): never put the 3-iteration loop inside one kernel —
// it spills ~0.5GB scratch. Per-iteration kernels are the sweet spot.
// ---------------------------------------------------------------------------

__global__ __launch_bounds__(256) void prep_all(
    const float* __restrict__ towers,
    const float* __restrict__ MWih, const float* __restrict__ MWhh,
    const float* __restrict__ UWih, const float* __restrict__ UWhh,
    const float* __restrict__ EnW1, const float* __restrict__ EnW2,
    const float* __restrict__ EeW1, const float* __restrict__ EeW2,
    const float* __restrict__ MBih, const float* __restrict__ MBhh,
    const float* __restrict__ UBih, const float* __restrict__ UBhh,
    const float* __restrict__ GWih, const float* __restrict__ GWhh,
    const float* __restrict__ GBih, const float* __restrict__ GBhh,
    ush* __restrict__ xh, ush* __restrict__ WIHe, ush* __restrict__ WTh,
    ush* __restrict__ WTu, ush* __restrict__ WBen1, ush* __restrict__ WBen2,
    ush* __restrict__ WBee1, ush* __restrict__ WBee2,
    float* __restrict__ biasM, float* __restrict__ biasU,
    float* __restrict__ WT_G, float* __restrict__ biasG)
{
  const int b = blockIdx.x, t = threadIdx.x;
  if (b < 2048) {                       // xh towers part: 32768*16
    const int idx = b * 256 + t;
    const int row = idx >> 4, kk = idx & 15;
    xh[row * 144 + kk] = f2u(kk < 14 ? towers[row * 14 + kk] : 0.f);
  } else if (b < 2480) {                // WIHe: 9*384*32 linear (edge Wih)
    const int idx = (b - 2048) * 256 + t;
    const int ck = idx / 12288, rem = idx % 12288, n = rem >> 5, kk = rem & 31;
    const int k = ck * 32 + kk;
    const int gate = n >> 7, c = n & 127;
    const int row = gate * 128 + c;
    int col = -1;
    if (k < 14)                    col = k;               // x_i
    else if (k >= 16 && k < 144)   col = 14 + (k - 16);   // h_i
    else if (k >= 144 && k < 158)  col = 142 + (k - 144); // x_j
    else if (k >= 160)             col = 156 + (k - 160); // h_j
    WIHe[idx] = f2u((col >= 0) ? MWih[row * 284 + col] : 0.f);
  } else if (b < 2672) {                // WTh: 4*384*32 linear
    const int idx = (b - 2480) * 256 + t;
    const int ck = idx / 12288, rem = idx % 12288, n = rem >> 5, kk = rem & 31;
    const int g = n >> 7, c = n & 127;
    WTh[idx] = f2u(MWhh[(g * 128 + c) * 128 + ck * 32 + kk]);
  } else if (b < 3248) {                // WTu: 9*512*32 swizzled
    const int idx = (b - 2672) * 256 + t;
    const int ck = idx >> 14, n = (idx >> 5) & 511, kk = idx & 31;
    const int k = ck * 32 + kk, gate = n >> 7, c = n & 127;
    float w = 0.f;
    const int row = (gate == 0) ? c : (gate == 1) ? 128 + c : 256 + c;
    if (k < 160) {
      int col = -1;
      if (k < 16)        { if (k < 14) col = k; }
      else if (k < 144)  col = 14 + (k - 16);
      if (gate != 3 && col >= 0) w = UWih[row * 142 + col];
    } else {
      if (gate != 2) w = UWhh[row * 128 + (k - 160)];
    }
    WTu[ck * 16384 + swz_idx(n, kk)] = f2u(w);
  } else if (b < 3264) {                // WBen1: 128x32 linear
    const int idx = (b - 3248) * 256 + t;
    const int n = (idx >> 5) & 127, kk = idx & 31;
    WBen1[idx] = f2u(kk < 14 ? EnW1[n * 14 + kk] : 0.f);
  } else if (b < 3328) {                // WBen2: 4*128*32 linear
    const int idx = (b - 3264) * 256 + t;
    const int ck = idx >> 12, n = (idx >> 5) & 127, kk = idx & 31;
    WBen2[idx] = f2u(EnW2[n * 128 + ck * 32 + kk]);
  } else if (b < 3344) {                // WBee1: 128x32 pair linear
    const int idx = (b - 3328) * 256 + t;
    const int n = (idx >> 5) & 127, kk = idx & 31;
    int col = (kk < 16) ? (kk < 14 ? kk : -1) : (kk < 30 ? 14 + (kk - 16) : -1);
    WBee1[idx] = f2u(col >= 0 ? EeW1[n * 28 + col] : 0.f);
    (void)n;
  } else if (b < 3408) {                // WBee2: 4*128*32 linear
    const int idx = (b - 3344) * 256 + t;
    const int ck = idx >> 12, n = (idx >> 5) & 127, kk = idx & 31;
    WBee2[idx] = f2u(EeW2[n * 128 + ck * 32 + kk]);
  } else if (b < 3410) {                // biasM [4 gates][128]
    const int idx = (b - 3408) * 256 + t;
    const int g = idx >> 7, c = idx & 127;
    float v;
    if (g == 0)      v = MBih[c] + MBhh[c];
    else if (g == 1) v = MBih[128 + c] + MBhh[128 + c];
    else if (g == 2) v = MBih[256 + c];
    else             v = MBhh[256 + c];
    biasM[idx] = v;
  } else if (b < 3412) {                // biasU
    const int idx = (b - 3410) * 256 + t;
    const int g = idx >> 7, c = idx & 127;
    float v;
    if (g == 0)      v = UBih[c] + UBhh[c];
    else if (g == 1) v = UBih[128 + c] + UBhh[128 + c];
    else if (g == 2) v = UBih[256 + c];
    else             v = UBhh[256 + c];
    biasU[idx] = v;
  } else if (b < 4180) {                // WT_G interleaved fp32: 384*512
    const int idx = (b - 3412) * 256 + t;
    const int kc = idx >> 9, cg = (idx >> 2) & 127, gate = idx & 3;
    const int row = (gate == 0) ? cg : (gate == 1) ? cg + 128 : cg + 256;
    float v = 0.f;
    if (kc < 256) { if (gate != 3) v = GWih[row * 256 + kc]; }
    else          { if (gate != 2) v = GWhh[row * 128 + (kc - 256)]; }
    WT_G[idx] = v;
  } else {                              // biasG
    const int idx = (b - 4180) * 256 + t;
    const int cg = idx >> 2, gate = idx & 3;
    float v;
    if (gate == 0)      v = GBih[cg] + GBhh[cg];
    else if (gate == 1) v = GBih[cg + 128] + GBhh[cg + 128];
    else if (gate == 2) v = GBih[cg + 256];
    else                v = GBhh[cg + 256];
    biasG[idx] = v;
  }
}

// ---------------------------------------------------------------------------
// Node encoder (E_n MLP): 64 node-rows per block, writes h to xh. (unchanged)
// ---------------------------------------------------------------------------
__global__ __launch_bounds__(256, 2) void enc_en(
    ush* __restrict__ xh,
    const ush* __restrict__ WB1, const float* __restrict__ b1,
    const ush* __restrict__ WB2, const float* __restrict__ b2)
{
  __shared__ ush smem[9216];           // A1 [0,1024) | Z1 [1024,9216)
  ush* A1 = smem;
  ush* Z1 = smem + 1024;
  const int t = threadIdx.x, lane = t & 63, w = t >> 6;
  const int rowBase = blockIdx.x * 64;
  const int quad = lane >> 4, l15 = lane & 15;

  {
    const int gm = t >> 2, gb = t & 3, grow = rowBase + gm;
    s16x8 v = z8();
    if (gb < 2) v = *(const s16x8*)(xh + grow * 144 + gb * 8);
    *(s16x8*)&A1[swz_blk(gm, gb)] = v;
  }
  __syncthreads();

  s16x8 af[4];
  #pragma unroll
  for (int rt = 0; rt < 4; ++rt)
    af[rt] = *(const s16x8*)&A1[swz_blk(rt * 16 + l15, quad)];
  f32x4 acc1[4][2];
  #pragma unroll
  for (int rt = 0; rt < 4; ++rt)
    #pragma unroll
    for (int ct = 0; ct < 2; ++ct) {
      #pragma unroll
      for (int q = 0; q < 4; ++q) acc1[rt][ct][q] = 0.f;
    }
  #pragma unroll
  for (int ct = 0; ct < 2; ++ct) {
    const int n = w * 32 + ct * 16 + l15;
    const s16x8 bf = *(const s16x8*)&WB1[n * 32 + quad * 8];
    #pragma unroll
    for (int rt = 0; rt < 4; ++rt) acc1[rt][ct] = MFMA(af[rt], bf, acc1[rt][ct]);
  }
  #pragma unroll
  for (int ct = 0; ct < 2; ++ct) {
    const int col = w * 32 + ct * 16 + l15;
    const int kk = col & 31;
    #pragma unroll
    for (int rt = 0; rt < 4; ++rt) {
      #pragma unroll
      for (int q = 0; q < 4; ++q) {
        const int m = rt * 16 + quad * 4 + q;
        Z1[w * 2048 + swz_idx(m, kk)] = f2u(tanh_f(acc1[rt][ct][q] + b1[col]));
      }
    }
  }
  __syncthreads();

  f32x4 acc2[4][2];
  #pragma unroll
  for (int rt = 0; rt < 4; ++rt)
    #pragma unroll
    for (int ct = 0; ct < 2; ++ct) {
      #pragma unroll
      for (int q = 0; q < 4; ++q) acc2[rt][ct][q] = 0.f;
    }
  for (int ck2 = 0; ck2 < 4; ++ck2) {
    #pragma unroll
    for (int rt = 0; rt < 4; ++rt)
      af[rt] = *(const s16x8*)&Z1[ck2 * 2048 + swz_blk(rt * 16 + l15, quad)];
    #pragma unroll
    for (int ct = 0; ct < 2; ++ct) {
      const int n = w * 32 + ct * 16 + l15;
      const s16x8 bf = *(const s16x8*)&WB2[(ck2 * 128 + n) * 32 + quad * 8];
      #pragma unroll
      for (int rt = 0; rt < 4; ++rt) acc2[rt][ct] = MFMA(af[rt], bf, acc2[rt][ct]);
    }
  }

  #pragma unroll
  for (int ct = 0; ct < 2; ++ct) {
    const int col = w * 32 + ct * 16 + l15;
    #pragma unroll
    for (int rt = 0; rt < 4; ++rt) {
      #pragma unroll
      for (int q = 0; q < 4; ++q) {
        const int r = rt * 16 + quad * 4 + q;
        xh[(rowBase + r) * 144 + 16 + col] = f2u(tanh_f(acc2[rt][ct][q] + b2[col]));
      }
    }
  }
}

// ---------------------------------------------------------------------------
// Ee MLP on the (i,i+1) pairs of 4 graphs (32 slots) -> e^0 into As_e.
// SC: A1 [0,1024) | Z1 [1024,5120) (4 wave-chunks of [32][32]).
// ---------------------------------------------------------------------------
DEV void ee_body(ush* As_e, ush* SC, const ush* __restrict__ xh,
                 const ush* __restrict__ WB1, const float* __restrict__ b1,
                 const ush* __restrict__ WB2, const float* __restrict__ b2,
                 int G0, int t)
{
  ush* A1 = SC;
  ush* Z1 = SC + 1024;
  const int lane = t & 63, w = t >> 6;
  const int quad = lane >> 4, l15 = lane & 15;

  {
    const int gm = t >> 3, gb = t & 7;
    if (gb < 4) {
      const int gg = gm >> 3, i = gm & 7;
      const int xi = (G0 + gg) * 8 + i;
      const int xj = (i < 7) ? xi + 1 : xi;
      const s16x8 v = (gb < 2) ? *(const s16x8*)(xh + xi * 144 + gb * 8)
                               : *(const s16x8*)(xh + xj * 144 + (gb - 2) * 8);
      *(s16x8*)&A1[swz_blk(gm, gb)] = v;
    }
  }
  __syncthreads();

  s16x8 af[2];
  #pragma unroll
  for (int rt = 0; rt < 2; ++rt)
    af[rt] = *(const s16x8*)&A1[swz_blk(rt * 16 + l15, quad)];
  f32x4 acc1[2][2];
  #pragma unroll
  for (int rt = 0; rt < 2; ++rt)
    #pragma unroll
    for (int ct = 0; ct < 2; ++ct) {
      #pragma unroll
      for (int q = 0; q < 4; ++q) acc1[rt][ct][q] = 0.f;
    }
  #pragma unroll
  for (int ct = 0; ct < 2; ++ct) {
    const int n = w * 32 + ct * 16 + l15;
    const s16x8 bf = *(const s16x8*)&WB1[n * 32 + quad * 8];
    #pragma unroll
    for (int rt = 0; rt < 2; ++rt) acc1[rt][ct] = MFMA(af[rt], bf, acc1[rt][ct]);
  }
  #pragma unroll
  for (int ct = 0; ct < 2; ++ct) {
    const int col = w * 32 + ct * 16 + l15;
    const int kk = col & 31;
    #pragma unroll
    for (int rt = 0; rt < 2; ++rt) {
      #pragma unroll
      for (int q = 0; q < 4; ++q) {
        const int m = rt * 16 + quad * 4 + q;
        Z1[w * 1024 + swz_idx(m, kk)] = f2u(tanh_f(acc1[rt][ct][q] + b1[col]));
      }
    }
  }
  __syncthreads();

  f32x4 acc2[2][2];
  #pragma unroll
  for (int rt = 0; rt < 2; ++rt)
    #pragma unroll
    for (int ct = 0; ct < 2; ++ct) {
      #pragma unroll
      for (int q = 0; q < 4; ++q) acc2[rt][ct][q] = 0.f;
    }
  for (int ck2 = 0; ck2 < 4; ++ck2) {
    #pragma unroll
    for (int rt = 0; rt < 2; ++rt)
      af[rt] = *(const s16x8*)&Z1[ck2 * 1024 + swz_blk(rt * 16 + l15, quad)];
    #pragma unroll
    for (int ct = 0; ct < 2; ++ct) {
      const int n = w * 32 + ct * 16 + l15;
      const s16x8 bf = *(const s16x8*)&WB2[(ck2 * 128 + n) * 32 + quad * 8];
      #pragma unroll
      for (int rt = 0; rt < 2; ++rt) acc2[rt][ct] = MFMA(af[rt], bf, acc2[rt][ct]);
    }
  }
  #pragma unroll
  for (int ct = 0; ct < 2; ++ct) {
    const int col = w * 32 + ct * 16 + l15;
    #pragma unroll
    for (int rt = 0; rt < 2; ++rt) {
      #pragma unroll
      for (int q = 0; q < 4; ++q) {
        const int r = rt * 16 + quad * 4 + q;
        As_e[(col >> 5) * 1024 + swz_idx(r, col & 31)] = f2u(tanh_f(acc2[rt][ct][q] + b2[col]));
      }
    }
  }
}

// ---------------------------------------------------------------------------
// Edge GRU core: D = WIHe·xx^T (9 ck) + WTh·e^T (4 ck) over 32 slots.
// As_e updated in place; eh carry unless LAST.
// ---------------------------------------------------------------------------
template<int LAST>
DEV void edge_core(ush* As_e, ush* Bxx, ush* __restrict__ eh,
                   const ush* __restrict__ WIHe, const ush* __restrict__ WTh,
                   const float* __restrict__ biasM,
                   const ush* __restrict__ xh, int G0, int t)
{
  const int lane = t & 63, w = t >> 6;
  const int quad = lane >> 4, l15 = lane & 15;
  const int ko = quad * 8;

  f32x4 accR[2][2], accZ[2][2], accN1[2][2], accN2[2][2];
  #pragma unroll
  for (int mt = 0; mt < 2; ++mt)
    #pragma unroll
    for (int nt = 0; nt < 2; ++nt) {
      #pragma unroll
      for (int q = 0; q < 4; ++q) { accR[mt][nt][q] = 0.f; accZ[mt][nt][q] = 0.f; accN1[mt][nt][q] = 0.f; accN2[mt][nt][q] = 0.f; }
    }

  auto stage_xx = [&](int ck) {
    const int gm = t >> 3, gb = t & 7;
    if (gb < 4) {
      const int gg = gm >> 3, i = gm & 7;
      const int xi = (G0 + gg) * 8 + i;
      const int xj = xi + ((i < 7) ? 1 : 0);
      const int k0 = ck * 32 + gb * 8;
      const s16x8 v = (k0 < 144) ? *(const s16x8*)(xh + xi * 144 + k0)
                                 : *(const s16x8*)(xh + xj * 144 + (k0 - 144));
      *(s16x8*)&Bxx[(ck & 1) * 1024 + swz_blk(gm, gb)] = v;
    }
  };

  // xx phase: K = 288 (9 chunks), gates r, z, n1
  stage_xx(0);
  __syncthreads();
  for (int ck = 0; ck < 9; ++ck) {
    if (ck + 1 < 9) stage_xx(ck + 1);
    const ush* Bc = Bxx + (ck & 1) * 1024;
    s16x8 be[2];
    #pragma unroll
    for (int nt = 0; nt < 2; ++nt)
      be[nt] = *(const s16x8*)&Bc[swz_blk(nt * 16 + l15, quad)];
    #pragma unroll
    for (int mt = 0; mt < 2; ++mt) {
      const int nb = w * 32 + mt * 16 + l15;
      const s16x8 aR = *(const s16x8*)&WIHe[(ck * 384 + nb) * 32 + ko];
      const s16x8 aZ = *(const s16x8*)&WIHe[(ck * 384 + 128 + nb) * 32 + ko];
      const s16x8 aN = *(const s16x8*)&WIHe[(ck * 384 + 256 + nb) * 32 + ko];
      #pragma unroll
      for (int nt = 0; nt < 2; ++nt) {
        accR[mt][nt]  = MFMA(aR, be[nt], accR[mt][nt]);
        accZ[mt][nt]  = MFMA(aZ, be[nt], accZ[mt][nt]);
        accN1[mt][nt] = MFMA(aN, be[nt], accN1[mt][nt]);
      }
    }
    __syncthreads();
  }

  // h phase: K = 128 (4 chunks) from As_e, gates r, z, n2
  #pragma unroll
  for (int ck = 0; ck < 4; ++ck) {
    s16x8 be[2];
    #pragma unroll
    for (int nt = 0; nt < 2; ++nt)
      be[nt] = *(const s16x8*)&As_e[ck * 1024 + swz_blk(nt * 16 + l15, quad)];
    #pragma unroll
    for (int mt = 0; mt < 2; ++mt) {
      const int nb = w * 32 + mt * 16 + l15;
      const s16x8 aR = *(const s16x8*)&WTh[(ck * 384 + nb) * 32 + ko];
      const s16x8 aZ = *(const s16x8*)&WTh[(ck * 384 + 128 + nb) * 32 + ko];
      const s16x8 aN = *(const s16x8*)&WTh[(ck * 384 + 256 + nb) * 32 + ko];
      #pragma unroll
      for (int nt = 0; nt < 2; ++nt) {
        accR[mt][nt]  = MFMA(aR, be[nt], accR[mt][nt]);
        accZ[mt][nt]  = MFMA(aZ, be[nt], accZ[mt][nt]);
        accN2[mt][nt] = MFMA(aN, be[nt], accN2[mt][nt]);
      }
    }
  }

  __syncthreads();   // all h-phase As_e reads complete before in-place update

  // epilogue: biases + GRU; in-place As_e update (1:1 thread ownership),
  // eh carry-out for valid slots unless LAST.
  #pragma unroll
  for (int mt = 0; mt < 2; ++mt) {
    const int hc0 = w * 32 + mt * 16 + quad * 4;
    const int ck2 = hc0 >> 5, kkB = hc0 & 31;
    #pragma unroll
    for (int nt = 0; nt < 2; ++nt) {
      const int erow = nt * 16 + l15;
      const int gg = erow >> 3, i = erow & 7;
      ush* cell = &As_e[ck2 * 1024 + swz_blk(erow, kkB >> 3) + (kkB & 7)];
      const u16x4 hp4 = *(const u16x4*)cell;
      u16x4 ov;
      #pragma unroll
      for (int q = 0; q < 4; ++q) {
        const int c = hc0 + q;
        const float rg = sigmoid_f(accR[mt][nt][q] + biasM[c]);
        const float zg = sigmoid_f(accZ[mt][nt][q] + biasM[128 + c]);
        const float nn = tanh_f(accN1[mt][nt][q] + biasM[256 + c]
                                + rg * (accN2[mt][nt][q] + biasM[384 + c]));
        const float hp = u2f(hp4[q]);
        ov[q] = f2u(nn + zg * (hp - nn));
      }
      *(u16x4*)cell = ov;
      if (!LAST && i < 7)
        *(u16x4*)&eh[(size_t)((G0 + gg) * 64 + i * 9 + 1) * 128 + hc0] = ov;
    }
  }
}

// ---------------------------------------------------------------------------
// Node GRU over 32 node rows, edges from As_e (LDS), WTu B direct-global.
// ---------------------------------------------------------------------------
DEV void node_lds(const ush* As_e, ush* SC, ush* __restrict__ xh,
                  const ush* __restrict__ WT, const float* __restrict__ bias,
                  int rowBase, int t)
{
  constexpr int NCH = 9, XCH = 5;
  const int lane = t & 63, w = t >> 6;
  const int l15 = lane & 15, quad = lane >> 4;

  f32x4 accR[2][2], accZ[2][2], accN1[2][2], accN2[2][2];
  #pragma unroll
  for (int rt = 0; rt < 2; ++rt)
    #pragma unroll
    for (int s = 0; s < 2; ++s) {
      #pragma unroll
      for (int q = 0; q < 4; ++q) { accR[rt][s][q] = 0.f; accZ[rt][s][q] = 0.f; accN1[rt][s][q] = 0.f; accN2[rt][s][q] = 0.f; }
    }

  auto stage = [&](int ck) {
    const int gm = t >> 3, gb = t & 7;
    if (gb < 4) {
      const int grow = rowBase + gm;
      const int k0 = ck * 32 + gb * 8;
      s16x8 v = z8();
      if (k0 < 16)       v = *(const s16x8*)(xh + grow * 144 + k0);
      else if (k0 < 144) {
        const int i = gm & 7;
        if (i < 7) {
          const int ke = k0 - 16;
          v = *(const s16x8*)&As_e[(ke >> 5) * 1024 + swz_blk(gm, (ke & 31) >> 3)];
        }
      } else if (k0 >= 160) {
        v = *(const s16x8*)(xh + grow * 144 + 16 + (k0 - 160));
      }
      *(s16x8*)&SC[(ck & 1) * 1024 + swz_blk(gm, gb)] = v;
    }
  };

  stage(0);
  __syncthreads();

  for (int ck = 0; ck < NCH; ++ck) {
    if (ck + 1 < NCH) stage(ck + 1);

    const ush* Wc = WT + ck * 16384;
    const ush* Ac = SC + (ck & 1) * 1024;
    s16x8 af[2];
    #pragma unroll
    for (int rt = 0; rt < 2; ++rt)
      af[rt] = *(const s16x8*)&Ac[swz_blk(rt * 16 + l15, quad)];
    if (ck < XCH) {
      #pragma unroll
      for (int s = 0; s < 2; ++s) {
        const int nb = w * 32 + s * 16 + l15;
        const s16x8 bR = *(const s16x8*)&Wc[swz_blk(0 * 128 + nb, quad)];
        const s16x8 bZ = *(const s16x8*)&Wc[swz_blk(1 * 128 + nb, quad)];
        const s16x8 bN = *(const s16x8*)&Wc[swz_blk(2 * 128 + nb, quad)];
        #pragma unroll
        for (int rt = 0; rt < 2; ++rt) {
          accR[rt][s]  = MFMA(af[rt], bR, accR[rt][s]);
          accZ[rt][s]  = MFMA(af[rt], bZ, accZ[rt][s]);
          accN1[rt][s] = MFMA(af[rt], bN, accN1[rt][s]);
        }
      }
    } else {
      #pragma unroll
      for (int s = 0; s < 2; ++s) {
        const int nb = w * 32 + s * 16 + l15;
        const s16x8 bR = *(const s16x8*)&Wc[swz_blk(0 * 128 + nb, quad)];
        const s16x8 bZ = *(const s16x8*)&Wc[swz_blk(1 * 128 + nb, quad)];
        const s16x8 bN = *(const s16x8*)&Wc[swz_blk(3 * 128 + nb, quad)];
        #pragma unroll
        for (int rt = 0; rt < 2; ++rt) {
          accR[rt][s]  = MFMA(af[rt], bR, accR[rt][s]);
          accZ[rt][s]  = MFMA(af[rt], bZ, accZ[rt][s]);
          accN2[rt][s] = MFMA(af[rt], bN, accN2[rt][s]);
        }
      }
    }
    __syncthreads();
  }

  #pragma unroll
  for (int s = 0; s < 2; ++s) {
    const int hcol = w * 32 + s * 16 + l15;
    const float bR = bias[hcol], bZ = bias[128 + hcol], bN1 = bias[256 + hcol], bN2 = bias[384 + hcol];
    #pragma unroll
    for (int rt = 0; rt < 2; ++rt) {
      #pragma unroll
      for (int q = 0; q < 4; ++q) {
        const int r = rt * 16 + quad * 4 + q;
        const int row = rowBase + r;
        const float hp = u2f(xh[row * 144 + 16 + hcol]);
        const float rg = sigmoid_f(accR[rt][s][q] + bR);
        const float zg = sigmoid_f(accZ[rt][s][q] + bZ);
        const float nn = tanh_f(accN1[rt][s][q] + bN1 + rg * (accN2[rt][s][q] + bN2));
        xh[row * 144 + 16 + hcol] = f2u(nn + zg * (hp - nn));
      }
    }
  }
}

// per-block readout: esum from As_e (final edges), hsum from xh (final h)
DEV void sums_body(const ush* As_e, const ush* __restrict__ xh,
                   float* __restrict__ hsum, float* __restrict__ esum,
                   int G0, int rowBase, int t)
{
  #pragma unroll
  for (int ii = 0; ii < 2; ++ii) {
    const int p = t + ii * 256;
    const int gg = p >> 7, hh = p & 127;
    float es = 0.f;
    #pragma unroll
    for (int i = 0; i < 7; ++i) {
      const int slot = gg * 8 + i;
      es += u2f(As_e[(hh >> 5) * 1024 + swz_idx(slot, hh & 31)]);
    }
    float hs = 0.f;
    #pragma unroll
    for (int i = 0; i < 8; ++i)
      hs += u2f(xh[(rowBase + gg * 8 + i) * 144 + 16 + hh]);
    hsum[(G0 + gg) * 128 + hh] = hs;
    esum[(G0 + gg) * 128 + hh] = es;
  }
}

// ---------------------------------------------------------------------------
// One fused GN iteration, 4 graphs / 32 rows per block (1024 blocks):
// [Ee MLP | eh load] -> edge GRU -> node GRU [-> sums]
// ---------------------------------------------------------------------------
template<int FIRST, int LAST>
__global__ __launch_bounds__(256, 2) void gn_iter(
    ush* __restrict__ eh, ush* __restrict__ xh,
    const ush* __restrict__ WIHe, const ush* __restrict__ WTh,
    const float* __restrict__ biasM,
    const ush* __restrict__ WTu, const float* __restrict__ biasU,
    const ush* __restrict__ WBee1, const float* __restrict__ bEe1,
    const ush* __restrict__ WBee2, const float* __restrict__ bEe2,
    float* __restrict__ hsum, float* __restrict__ esum)
{
  __shared__ ush smem[9216];           // As_e [0,4096) | SC [4096,9216)
  ush* As_e = smem;
  ush* SC   = smem + 4096;
  const int t = threadIdx.x;
  const int G0 = blockIdx.x * 4, rowBase = blockIdx.x * 32;

  if (FIRST) {
    ee_body(As_e, SC, xh, WBee1, bEe1, WBee2, bEe2, G0, t);
  } else {
    const int gm = t >> 3, gb = t & 7;
    if (gb < 4) {
      const int gg = gm >> 3, i = gm & 7;
      const ush* src = eh + (size_t)((G0 + gg) * 64 + i * 9 + 1) * 128;
      #pragma unroll
      for (int ck = 0; ck < 4; ++ck) {
        s16x8 v = z8();
        if (i < 7) v = *(const s16x8*)(src + ck * 32 + gb * 8);
        *(s16x8*)&As_e[ck * 1024 + swz_blk(gm, gb)] = v;
      }
    }
  }
  __syncthreads();

  edge_core<LAST>(As_e, SC, eh, WIHe, WTh, biasM, xh, G0, t);
  __syncthreads();

  node_lds(As_e, SC, xh, WTu, biasU, rowBase, t);

  if (LAST) {
    __syncthreads();
    sums_body(As_e, xh, hsum, esum, G0, rowBase, t);
  }
}

// global GRU (h_prev = 0) fused with output head: 16 graphs per block.
__global__ __launch_bounds__(256) void gru_global_out(
    const float* __restrict__ hsum, const float* __restrict__ esum,
    const float* __restrict__ WT, const float* __restrict__ bias,
    const float* __restrict__ OW, const float* __restrict__ Ob,
    float* __restrict__ out)
{
  constexpr int KT = 384;
  __shared__ float4 ATl4[KT * 4];
  __shared__ float4 Bl4[16 * 128];
  __shared__ float gmat[16 * 128];
  __shared__ float red[16 * 4];
  float* ATl = (float*)ATl4;
  const int t = threadIdx.x;
  const int rowBase = blockIdx.x * 16;
  for (int idx = t; idx < KT * 16; idx += 256) {
    const int kc = idx >> 4, r = idx & 15, grow = rowBase + r;
    float v = 0.f;
    if (kc < 128)      v = hsum[grow * 128 + kc];
    else if (kc < 256) v = esum[grow * 128 + (kc - 128)];
    ATl[idx] = v;
  }
  const int c = t & 127, rh = t >> 7;
  float accR[8], accZ[8], accN1[8];
  #pragma unroll
  for (int rr = 0; rr < 8; ++rr) { accR[rr] = 0.f; accZ[rr] = 0.f; accN1[rr] = 0.f; }
  const float4* WT4 = (const float4*)WT;
  for (int ck = 0; ck < 16; ++ck) {
    __syncthreads();
    #pragma unroll
    for (int ii = 0; ii < 8; ++ii) { const int idx = t + ii * 256; Bl4[idx] = WT4[ck * 2048 + idx]; }
    __syncthreads();
    const int kb = ck * 16;
    #pragma unroll
    for (int kcl = 0; kcl < 16; ++kcl) {
      const float4 wv = Bl4[kcl * 128 + c];
      const float4 a0 = ATl4[(kb + kcl) * 4 + rh * 2];
      const float4 a1 = ATl4[(kb + kcl) * 4 + rh * 2 + 1];
      const float av[8] = {a0.x, a0.y, a0.z, a0.w, a1.x, a1.y, a1.z, a1.w};
      #pragma unroll
      for (int rr = 0; rr < 8; ++rr) {
        accR[rr]  += wv.x * av[rr];
        accZ[rr]  += wv.y * av[rr];
        accN1[rr] += wv.z * av[rr];
      }
    }
  }
  const float4 bb = ((const float4*)bias)[c];
  const float ow = OW[c];
  #pragma unroll
  for (int rr = 0; rr < 8; ++rr) {
    const float rg = sigmoid_f(accR[rr] + bb.x);
    const float zg = sigmoid_f(accZ[rr] + bb.y);
    const float nn = tanh_f(accN1[rr] + bb.z + rg * bb.w);
    gmat[(rh * 8 + rr) * 128 + c] = (1.f - zg) * nn * ow;
  }
  __syncthreads();
  if (t < 64) {
    const int r = t >> 2, part = t & 3;
    float s = 0.f;
    #pragma unroll
    for (int cc = 0; cc < 32; ++cc) s += gmat[r * 128 + part * 32 + cc];
    red[r * 4 + part] = s;
  }
  __syncthreads();
  if (t < 16) {
    const float s = red[t * 4] + red[t * 4 + 1] + red[t * 4 + 2] + red[t * 4 + 3];
    out[rowBase + t] = sigmoid_f(s + Ob[0]);
  }
}

// ---------------------------------------------------------------------------
extern "C" void kernel_launch(void* const* d_in, const int* in_sizes, int n_in,
                              void* d_out, int out_size, void* d_ws, size_t ws_size,
                              hipStream_t stream)
{
  (void)in_sizes; (void)n_in; (void)out_size; (void)ws_size;
  const float* towers = (const float*)d_in[0];
  const float* EnW1 = (const float*)d_in[1];
  const float* EnB1 = (const float*)d_in[2];
  const float* EnW2 = (const float*)d_in[3];
  const float* EnB2 = (const float*)d_in[4];
  const float* EeW1 = (const float*)d_in[5];
  const float* EeB1 = (const float*)d_in[6];
  const float* EeW2 = (const float*)d_in[7];
  const float* EeB2 = (const float*)d_in[8];
  const float* UWih = (const float*)d_in[9];
  const float* UWhh = (const float*)d_in[10];
  const float* UBih = (const float*)d_in[11];
  const float* UBhh = (const float*)d_in[12];
  const float* MWih = (const float*)d_in[13];
  const float* MWhh = (const float*)d_in[14];
  const float* MBih = (const float*)d_in[15];
  const float* MBhh = (const float*)d_in[16];
  const float* GWih = (const float*)d_in[17];
  const float* GWhh = (const float*)d_in[18];
  const float* GBih = (const float*)d_in[19];
  const float* GBhh = (const float*)d_in[20];
  const float* OW   = (const float*)d_in[21];
  const float* Ob   = (const float*)d_in[22];

  char* ws = (char*)d_ws;
  size_t off = 0;
  auto take = [&](size_t b) { void* p = ws + off; off = (off + b + 255) & ~(size_t)255; return p; };
  ush*   xh     = (ush*)take((size_t)32768 * 144 * 2);
  ush*   eh     = (ush*)take((size_t)262144 * 128 * 2);
  float* hsum   = (float*)take((size_t)4096 * 128 * 4);
  float* esum   = (float*)take((size_t)4096 * 128 * 4);
  ush*   WIHe   = (ush*)take((size_t)9 * 384 * 32 * 2);
  ush*   WTh    = (ush*)take((size_t)4 * 384 * 32 * 2);
  ush*   WTu    = (ush*)take((size_t)9 * 512 * 32 * 2);
  ush*   WBen1  = (ush*)take((size_t)128 * 32 * 2);
  ush*   WBen2  = (ush*)take((size_t)4 * 128 * 32 * 2);
  ush*   WBee1  = (ush*)take((size_t)128 * 32 * 2);
  ush*   WBee2  = (ush*)take((size_t)4 * 128 * 32 * 2);
  float* biasM  = (float*)take(512 * 4);
  float* biasU  = (float*)take(512 * 4);
  float* WT_G   = (float*)take((size_t)384 * 512 * 4);
  float* biasG  = (float*)take(512 * 4);

  prep_all<<<4182, 256, 0, stream>>>(
      towers, MWih, MWhh, UWih, UWhh, EnW1, EnW2, EeW1, EeW2,
      MBih, MBhh, UBih, UBhh, GWih, GWhh, GBih, GBhh,
      xh, WIHe, WTh, WTu, WBen1, WBen2, WBee1, WBee2,
      biasM, biasU, WT_G, biasG);

  // node encoder
  enc_en<<<512, 256, 0, stream>>>(xh, WBen1, EnB1, WBen2, EnB2);

  // fused iterations: [Ee | eh] -> edge GRU -> node GRU [-> sums]
  gn_iter<1, 0><<<1024, 256, 0, stream>>>(eh, xh, WIHe, WTh, biasM, WTu, biasU,
                                          WBee1, EeB1, WBee2, EeB2, hsum, esum);
  gn_iter<0, 0><<<1024, 256, 0, stream>>>(eh, xh, WIHe, WTh, biasM, WTu, biasU,
                                          WBee1, EeB1, WBee2, EeB2, hsum, esum);
  gn_iter<0, 1><<<1024, 256, 0, stream>>>(eh, xh, WIHe, WTh, biasM, WTu, biasU,
                                          WBee1, EeB1, WBee2, EeB2, hsum, esum);

  gru_global_out<<<256, 256, 0, stream>>>(hsum, esum, WT_G, biasG, OW, Ob, (float*)d_out);
}

// Round 13
// 241.262 us; speedup vs baseline: 1.9441x; 1.1791x over previous
//
#include <hip/hip_runtime.h>
#include <hip/hip_bf16.h>

typedef __hip_bfloat16 bf16;
typedef unsigned short ush;
typedef short s16x8 __attribute__((ext_vector_type(8)));
typedef ush u16x4 __attribute__((ext_vector_type(4)));
typedef float f32x4 __attribute__((ext_vector_type(4)));

#define DEV __device__ __forceinline__

DEV float rcp_f(float x) { return __builtin_amdgcn_rcpf(x); }
DEV float sigmoid_f(float x) { return rcp_f(1.f + __expf(-x)); }
DEV float tanh_f(float x) { return 1.f - 2.f * rcp_f(__expf(2.f * x) + 1.f); }

DEV float u2f(ush u) { unsigned int v = ((unsigned int)u) << 16; float f; __builtin_memcpy(&f, &v, 4); return f; }
DEV ush f2u(float f) { bf16 h = __float2bfloat16(f); ush u; __builtin_memcpy(&u, &h, 2); return u; }

DEV f32x4 MFMA(s16x8 a, s16x8 b, f32x4 c) {
  return __builtin_amdgcn_mfma_f32_16x16x32_bf16(a, b, c, 0, 0, 0);
}

DEV s16x8 z8() {
  s16x8 v;
  for (int z = 0; z < 8; ++z) v[z] = 0;
  return v;
}

// swizzled element index within a [rows][32] bf16 chunk: 16B blocks XOR'd by (row>>1)&3
DEV int swz_idx(int row, int kk) { return row * 32 + (((kk >> 3) ^ ((row >> 1) & 3)) << 3) + (kk & 7); }
DEV int swz_blk(int row, int blk) { return row * 32 + ((blk ^ ((row >> 1) & 3)) << 3); }

// ---------------------------------------------------------------------------
// N=4096 graphs, K=8 nodes, n_in=14, H=128, k=3 iters. Inputs fp32.
// xh:  [32768][144] bf16 = [towers(14), pad(2), h(128)]
// eh:  iteration-carry only (rows g*64 + i*9+1).
// PER-ITERATION FUSION (gn_iter<FIRST,LAST>, 512 blocks x 8 graphs, the R10
// sweet spot — R12's 4-graph blocks regressed: phase count unchanged, less
// work per phase). THIS ROUND: FULL-WIDTH OPERAND STAGING — the 288-wide xx
// (and node input) is staged once into BX (36KB LDS), then all 9 MFMA rounds
// run back-to-back with NO barriers, letting the compiler pipeline the LDS
// reads + direct-global B loads. Barriers/iter: ~22 -> ~7 (R10/R12 showed
// the serialized stage->barrier->burst chain was the latency floor).
// Fusion law (R8/R11): per-iteration kernels only; 3-iter loop in one
// kernel spills ~0.5GB scratch.
// ---------------------------------------------------------------------------

__global__ __launch_bounds__(256) void prep_all(
    const float* __restrict__ towers,
    const float* __restrict__ MWih, const float* __restrict__ MWhh,
    const float* __restrict__ UWih, const float* __restrict__ UWhh,
    const float* __restrict__ EnW1, const float* __restrict__ EnW2,
    const float* __restrict__ EeW1, const float* __restrict__ EeW2,
    const float* __restrict__ MBih, const float* __restrict__ MBhh,
    const float* __restrict__ UBih, const float* __restrict__ UBhh,
    const float* __restrict__ GWih, const float* __restrict__ GWhh,
    const float* __restrict__ GBih, const float* __restrict__ GBhh,
    ush* __restrict__ xh, ush* __restrict__ WIHe, ush* __restrict__ WTh,
    ush* __restrict__ WTu, ush* __restrict__ WBen1, ush* __restrict__ WBen2,
    ush* __restrict__ WBee1, ush* __restrict__ WBee2,
    float* __restrict__ biasM, float* __restrict__ biasU,
    float* __restrict__ WT_G, float* __restrict__ biasG)
{
  const int b = blockIdx.x, t = threadIdx.x;
  if (b < 2048) {                       // xh towers part: 32768*16
    const int idx = b * 256 + t;
    const int row = idx >> 4, kk = idx & 15;
    xh[row * 144 + kk] = f2u(kk < 14 ? towers[row * 14 + kk] : 0.f);
  } else if (b < 2480) {                // WIHe: 9*384*32 linear (edge Wih)
    const int idx = (b - 2048) * 256 + t;
    const int ck = idx / 12288, rem = idx % 12288, n = rem >> 5, kk = rem & 31;
    const int k = ck * 32 + kk;
    const int gate = n >> 7, c = n & 127;
    const int row = gate * 128 + c;
    int col = -1;
    if (k < 14)                    col = k;               // x_i
    else if (k >= 16 && k < 144)   col = 14 + (k - 16);   // h_i
    else if (k >= 144 && k < 158)  col = 142 + (k - 144); // x_j
    else if (k >= 160)             col = 156 + (k - 160); // h_j
    WIHe[idx] = f2u((col >= 0) ? MWih[row * 284 + col] : 0.f);
  } else if (b < 2672) {                // WTh: 4*384*32 linear
    const int idx = (b - 2480) * 256 + t;
    const int ck = idx / 12288, rem = idx % 12288, n = rem >> 5, kk = rem & 31;
    const int g = n >> 7, c = n & 127;
    WTh[idx] = f2u(MWhh[(g * 128 + c) * 128 + ck * 32 + kk]);
  } else if (b < 3248) {                // WTu: 9*512*32 swizzled
    const int idx = (b - 2672) * 256 + t;
    const int ck = idx >> 14, n = (idx >> 5) & 511, kk = idx & 31;
    const int k = ck * 32 + kk, gate = n >> 7, c = n & 127;
    float w = 0.f;
    const int row = (gate == 0) ? c : (gate == 1) ? 128 + c : 256 + c;
    if (k < 160) {
      int col = -1;
      if (k < 16)        { if (k < 14) col = k; }
      else if (k < 144)  col = 14 + (k - 16);
      if (gate != 3 && col >= 0) w = UWih[row * 142 + col];
    } else {
      if (gate != 2) w = UWhh[row * 128 + (k - 160)];
    }
    WTu[ck * 16384 + swz_idx(n, kk)] = f2u(w);
  } else if (b < 3264) {                // WBen1: 128x32 linear
    const int idx = (b - 3248) * 256 + t;
    const int n = (idx >> 5) & 127, kk = idx & 31;
    WBen1[idx] = f2u(kk < 14 ? EnW1[n * 14 + kk] : 0.f);
  } else if (b < 3328) {                // WBen2: 4*128*32 linear
    const int idx = (b - 3264) * 256 + t;
    const int ck = idx >> 12, n = (idx >> 5) & 127, kk = idx & 31;
    WBen2[idx] = f2u(EnW2[n * 128 + ck * 32 + kk]);
  } else if (b < 3344) {                // WBee1: 128x32 pair linear
    const int idx = (b - 3328) * 256 + t;
    const int n = (idx >> 5) & 127, kk = idx & 31;
    int col = (kk < 16) ? (kk < 14 ? kk : -1) : (kk < 30 ? 14 + (kk - 16) : -1);
    WBee1[idx] = f2u(col >= 0 ? EeW1[n * 28 + col] : 0.f);
    (void)n;
  } else if (b < 3408) {                // WBee2: 4*128*32 linear
    const int idx = (b - 3344) * 256 + t;
    const int ck = idx >> 12, n = (idx >> 5) & 127, kk = idx & 31;
    WBee2[idx] = f2u(EeW2[n * 128 + ck * 32 + kk]);
  } else if (b < 3410) {                // biasM [4 gates][128]
    const int idx = (b - 3408) * 256 + t;
    const int g = idx >> 7, c = idx & 127;
    float v;
    if (g == 0)      v = MBih[c] + MBhh[c];
    else if (g == 1) v = MBih[128 + c] + MBhh[128 + c];
    else if (g == 2) v = MBih[256 + c];
    else             v = MBhh[256 + c];
    biasM[idx] = v;
  } else if (b < 3412) {                // biasU
    const int idx = (b - 3410) * 256 + t;
    const int g = idx >> 7, c = idx & 127;
    float v;
    if (g == 0)      v = UBih[c] + UBhh[c];
    else if (g == 1) v = UBih[128 + c] + UBhh[128 + c];
    else if (g == 2) v = UBih[256 + c];
    else             v = UBhh[256 + c];
    biasU[idx] = v;
  } else if (b < 4180) {                // WT_G interleaved fp32: 384*512
    const int idx = (b - 3412) * 256 + t;
    const int kc = idx >> 9, cg = (idx >> 2) & 127, gate = idx & 3;
    const int row = (gate == 0) ? cg : (gate == 1) ? cg + 128 : cg + 256;
    float v = 0.f;
    if (kc < 256) { if (gate != 3) v = GWih[row * 256 + kc]; }
    else          { if (gate != 2) v = GWhh[row * 128 + (kc - 256)]; }
    WT_G[idx] = v;
  } else {                              // biasG
    const int idx = (b - 4180) * 256 + t;
    const int cg = idx >> 2, gate = idx & 3;
    float v;
    if (gate == 0)      v = GBih[cg] + GBhh[cg];
    else if (gate == 1) v = GBih[cg + 128] + GBhh[cg + 128];
    else if (gate == 2) v = GBih[cg + 256];
    else                v = GBhh[cg + 256];
    biasG[idx] = v;
  }
}

// ---------------------------------------------------------------------------
// Node encoder (E_n MLP): 64 node-rows per block, writes h to xh.
// ---------------------------------------------------------------------------
__global__ __launch_bounds__(256, 2) void enc_en(
    ush* __restrict__ xh,
    const ush* __restrict__ WB1, const float* __restrict__ b1,
    const ush* __restrict__ WB2, const float* __restrict__ b2)
{
  __shared__ ush smem[9216];           // A1 [0,1024) | Z1 [1024,9216)
  ush* A1 = smem;
  ush* Z1 = smem + 1024;
  const int t = threadIdx.x, lane = t & 63, w = t >> 6;
  const int rowBase = blockIdx.x * 64;
  const int quad = lane >> 4, l15 = lane & 15;

  {
    const int gm = t >> 2, gb = t & 3, grow = rowBase + gm;
    s16x8 v = z8();
    if (gb < 2) v = *(const s16x8*)(xh + grow * 144 + gb * 8);
    *(s16x8*)&A1[swz_blk(gm, gb)] = v;
  }
  __syncthreads();

  s16x8 af[4];
  #pragma unroll
  for (int rt = 0; rt < 4; ++rt)
    af[rt] = *(const s16x8*)&A1[swz_blk(rt * 16 + l15, quad)];
  f32x4 acc1[4][2];
  #pragma unroll
  for (int rt = 0; rt < 4; ++rt)
    #pragma unroll
    for (int ct = 0; ct < 2; ++ct) {
      #pragma unroll
      for (int q = 0; q < 4; ++q) acc1[rt][ct][q] = 0.f;
    }
  #pragma unroll
  for (int ct = 0; ct < 2; ++ct) {
    const int n = w * 32 + ct * 16 + l15;
    const s16x8 bf = *(const s16x8*)&WB1[n * 32 + quad * 8];
    #pragma unroll
    for (int rt = 0; rt < 4; ++rt) acc1[rt][ct] = MFMA(af[rt], bf, acc1[rt][ct]);
  }
  #pragma unroll
  for (int ct = 0; ct < 2; ++ct) {
    const int col = w * 32 + ct * 16 + l15;
    const int kk = col & 31;
    #pragma unroll
    for (int rt = 0; rt < 4; ++rt) {
      #pragma unroll
      for (int q = 0; q < 4; ++q) {
        const int m = rt * 16 + quad * 4 + q;
        Z1[w * 2048 + swz_idx(m, kk)] = f2u(tanh_f(acc1[rt][ct][q] + b1[col]));
      }
    }
  }
  __syncthreads();

  f32x4 acc2[4][2];
  #pragma unroll
  for (int rt = 0; rt < 4; ++rt)
    #pragma unroll
    for (int ct = 0; ct < 2; ++ct) {
      #pragma unroll
      for (int q = 0; q < 4; ++q) acc2[rt][ct][q] = 0.f;
    }
  for (int ck2 = 0; ck2 < 4; ++ck2) {
    #pragma unroll
    for (int rt = 0; rt < 4; ++rt)
      af[rt] = *(const s16x8*)&Z1[ck2 * 2048 + swz_blk(rt * 16 + l15, quad)];
    #pragma unroll
    for (int ct = 0; ct < 2; ++ct) {
      const int n = w * 32 + ct * 16 + l15;
      const s16x8 bf = *(const s16x8*)&WB2[(ck2 * 128 + n) * 32 + quad * 8];
      #pragma unroll
      for (int rt = 0; rt < 4; ++rt) acc2[rt][ct] = MFMA(af[rt], bf, acc2[rt][ct]);
    }
  }

  #pragma unroll
  for (int ct = 0; ct < 2; ++ct) {
    const int col = w * 32 + ct * 16 + l15;
    #pragma unroll
    for (int rt = 0; rt < 4; ++rt) {
      #pragma unroll
      for (int q = 0; q < 4; ++q) {
        const int r = rt * 16 + quad * 4 + q;
        xh[(rowBase + r) * 144 + 16 + col] = f2u(tanh_f(acc2[rt][ct][q] + b2[col]));
      }
    }
  }
}

// ---------------------------------------------------------------------------
// Ee MLP on the (i,i+1) pairs -> e^0 into As_e (B-operand layout).
// SC: A1 [0,1024) | Z1 [1024,9216).
// ---------------------------------------------------------------------------
DEV void ee_body(ush* As_e, ush* SC, const ush* __restrict__ xh,
                 const ush* __restrict__ WB1, const float* __restrict__ b1,
                 const ush* __restrict__ WB2, const float* __restrict__ b2,
                 int G0, int t)
{
  ush* A1 = SC;
  ush* Z1 = SC + 1024;
  const int lane = t & 63, w = t >> 6;
  const int quad = lane >> 4, l15 = lane & 15;

  {
    const int gm = t >> 2, gb = t & 3;
    const int gg = gm >> 3, i = gm & 7;
    const int xi = (G0 + gg) * 8 + i;
    const int xj = (i < 7) ? xi + 1 : xi;
    const s16x8 v = (gb < 2) ? *(const s16x8*)(xh + xi * 144 + gb * 8)
                             : *(const s16x8*)(xh + xj * 144 + (gb - 2) * 8);
    *(s16x8*)&A1[swz_blk(gm, gb)] = v;
  }
  __syncthreads();

  s16x8 af[4];
  #pragma unroll
  for (int rt = 0; rt < 4; ++rt)
    af[rt] = *(const s16x8*)&A1[swz_blk(rt * 16 + l15, quad)];
  f32x4 acc1[4][2];
  #pragma unroll
  for (int rt = 0; rt < 4; ++rt)
    #pragma unroll
    for (int ct = 0; ct < 2; ++ct) {
      #pragma unroll
      for (int q = 0; q < 4; ++q) acc1[rt][ct][q] = 0.f;
    }
  #pragma unroll
  for (int ct = 0; ct < 2; ++ct) {
    const int n = w * 32 + ct * 16 + l15;
    const s16x8 bf = *(const s16x8*)&WB1[n * 32 + quad * 8];
    #pragma unroll
    for (int rt = 0; rt < 4; ++rt) acc1[rt][ct] = MFMA(af[rt], bf, acc1[rt][ct]);
  }
  #pragma unroll
  for (int ct = 0; ct < 2; ++ct) {
    const int col = w * 32 + ct * 16 + l15;
    const int kk = col & 31;
    #pragma unroll
    for (int rt = 0; rt < 4; ++rt) {
      #pragma unroll
      for (int q = 0; q < 4; ++q) {
        const int m = rt * 16 + quad * 4 + q;
        Z1[w * 2048 + swz_idx(m, kk)] = f2u(tanh_f(acc1[rt][ct][q] + b1[col]));
      }
    }
  }
  __syncthreads();

  f32x4 acc2[4][2];
  #pragma unroll
  for (int rt = 0; rt < 4; ++rt)
    #pragma unroll
    for (int ct = 0; ct < 2; ++ct) {
      #pragma unroll
      for (int q = 0; q < 4; ++q) acc2[rt][ct][q] = 0.f;
    }
  for (int ck2 = 0; ck2 < 4; ++ck2) {
    #pragma unroll
    for (int rt = 0; rt < 4; ++rt)
      af[rt] = *(const s16x8*)&Z1[ck2 * 2048 + swz_blk(rt * 16 + l15, quad)];
    #pragma unroll
    for (int ct = 0; ct < 2; ++ct) {
      const int n = w * 32 + ct * 16 + l15;
      const s16x8 bf = *(const s16x8*)&WB2[(ck2 * 128 + n) * 32 + quad * 8];
      #pragma unroll
      for (int rt = 0; rt < 4; ++rt) acc2[rt][ct] = MFMA(af[rt], bf, acc2[rt][ct]);
    }
  }
  #pragma unroll
  for (int ct = 0; ct < 2; ++ct) {
    const int col = w * 32 + ct * 16 + l15;
    #pragma unroll
    for (int rt = 0; rt < 4; ++rt) {
      #pragma unroll
      for (int q = 0; q < 4; ++q) {
        const int r = rt * 16 + quad * 4 + q;
        As_e[(col >> 5) * 2048 + swz_idx(r, col & 31)] = f2u(tanh_f(acc2[rt][ct][q] + b2[col]));
      }
    }
  }
}

// ---------------------------------------------------------------------------
// Edge GRU core: full-width xx staged to BX (36KB) ONCE, then 9 MFMA rounds
// with no barriers; h phase from As_e; in-place As_e update; eh carry unless
// LAST.
// ---------------------------------------------------------------------------
template<int LAST>
DEV void edge_core(ush* As_e, ush* BX, ush* __restrict__ eh,
                   const ush* __restrict__ WIHe, const ush* __restrict__ WTh,
                   const float* __restrict__ biasM,
                   const ush* __restrict__ xh, int G0, int t)
{
  const int lane = t & 63, w = t >> 6;
  const int quad = lane >> 4, l15 = lane & 15;
  const int ko = quad * 8;

  f32x4 accR[2][4], accZ[2][4], accN1[2][4], accN2[2][4];
  #pragma unroll
  for (int mt = 0; mt < 2; ++mt)
    #pragma unroll
    for (int nt = 0; nt < 4; ++nt) {
      #pragma unroll
      for (int q = 0; q < 4; ++q) { accR[mt][nt][q] = 0.f; accZ[mt][nt][q] = 0.f; accN1[mt][nt][q] = 0.f; accN2[mt][nt][q] = 0.f; }
    }

  // stage ALL 9 xx chunks (K=288) into BX, one barrier
  {
    const int gm = t >> 2, gb = t & 3;
    const int gg = gm >> 3, i = gm & 7;
    const int xi = (G0 + gg) * 8 + i;
    const int xj = xi + ((i < 7) ? 1 : 0);
    #pragma unroll
    for (int ck = 0; ck < 9; ++ck) {
      const int k0 = ck * 32 + gb * 8;
      const s16x8 v = (k0 < 144) ? *(const s16x8*)(xh + xi * 144 + k0)
                                 : *(const s16x8*)(xh + xj * 144 + (k0 - 144));
      *(s16x8*)&BX[ck * 2048 + swz_blk(gm, gb)] = v;
    }
  }
  __syncthreads();

  // xx phase: 9 rounds, no barriers — compiler pipelines LDS + global loads
  #pragma unroll
  for (int ck = 0; ck < 9; ++ck) {
    s16x8 be[4];
    #pragma unroll
    for (int nt = 0; nt < 4; ++nt)
      be[nt] = *(const s16x8*)&BX[ck * 2048 + swz_blk(nt * 16 + l15, quad)];
    #pragma unroll
    for (int mt = 0; mt < 2; ++mt) {
      const int nb = w * 32 + mt * 16 + l15;
      const s16x8 aR = *(const s16x8*)&WIHe[(ck * 384 + nb) * 32 + ko];
      const s16x8 aZ = *(const s16x8*)&WIHe[(ck * 384 + 128 + nb) * 32 + ko];
      const s16x8 aN = *(const s16x8*)&WIHe[(ck * 384 + 256 + nb) * 32 + ko];
      #pragma unroll
      for (int nt = 0; nt < 4; ++nt) {
        accR[mt][nt]  = MFMA(aR, be[nt], accR[mt][nt]);
        accZ[mt][nt]  = MFMA(aZ, be[nt], accZ[mt][nt]);
        accN1[mt][nt] = MFMA(aN, be[nt], accN1[mt][nt]);
      }
    }
  }

  // h phase: K = 128 (4 chunks) from As_e, gates r, z, n2
  #pragma unroll
  for (int ck = 0; ck < 4; ++ck) {
    s16x8 be[4];
    #pragma unroll
    for (int nt = 0; nt < 4; ++nt)
      be[nt] = *(const s16x8*)&As_e[ck * 2048 + swz_blk(nt * 16 + l15, quad)];
    #pragma unroll
    for (int mt = 0; mt < 2; ++mt) {
      const int nb = w * 32 + mt * 16 + l15;
      const s16x8 aR = *(const s16x8*)&WTh[(ck * 384 + nb) * 32 + ko];
      const s16x8 aZ = *(const s16x8*)&WTh[(ck * 384 + 128 + nb) * 32 + ko];
      const s16x8 aN = *(const s16x8*)&WTh[(ck * 384 + 256 + nb) * 32 + ko];
      #pragma unroll
      for (int nt = 0; nt < 4; ++nt) {
        accR[mt][nt]  = MFMA(aR, be[nt], accR[mt][nt]);
        accZ[mt][nt]  = MFMA(aZ, be[nt], accZ[mt][nt]);
        accN2[mt][nt] = MFMA(aN, be[nt], accN2[mt][nt]);
      }
    }
  }

  __syncthreads();   // all h-phase As_e reads complete before in-place update

  // epilogue: biases + GRU; in-place As_e update (1:1 thread ownership),
  // eh carry-out for valid slots unless LAST.
  #pragma unroll
  for (int mt = 0; mt < 2; ++mt) {
    const int hc0 = w * 32 + mt * 16 + quad * 4;
    const int ck2 = hc0 >> 5, kkB = hc0 & 31;
    #pragma unroll
    for (int nt = 0; nt < 4; ++nt) {
      const int erow = nt * 16 + l15;
      const int gg = erow >> 3, i = erow & 7;
      ush* cell = &As_e[ck2 * 2048 + swz_blk(erow, kkB >> 3) + (kkB & 7)];
      const u16x4 hp4 = *(const u16x4*)cell;
      u16x4 ov;
      #pragma unroll
      for (int q = 0; q < 4; ++q) {
        const int c = hc0 + q;
        const float rg = sigmoid_f(accR[mt][nt][q] + biasM[c]);
        const float zg = sigmoid_f(accZ[mt][nt][q] + biasM[128 + c]);
        const float nn = tanh_f(accN1[mt][nt][q] + biasM[256 + c]
                                + rg * (accN2[mt][nt][q] + biasM[384 + c]));
        const float hp = u2f(hp4[q]);
        ov[q] = f2u(nn + zg * (hp - nn));
      }
      *(u16x4*)cell = ov;
      if (!LAST && i < 7)
        *(u16x4*)&eh[(size_t)((G0 + gg) * 64 + i * 9 + 1) * 128 + hc0] = ov;
    }
  }
}

// ---------------------------------------------------------------------------
// Node GRU: full 288-wide input staged to BX once, then 9 MFMA rounds with
// no barriers (WTu B direct-global); edges from As_e (LDS).
// ---------------------------------------------------------------------------
DEV void node_lds(const ush* As_e, ush* BX, ush* __restrict__ xh,
                  const ush* __restrict__ WT, const float* __restrict__ bias,
                  int rowBase, int t)
{
  constexpr int NCH = 9, XCH = 5;
  const int lane = t & 63, w = t >> 6;
  const int l15 = lane & 15, quad = lane >> 4;

  f32x4 accR[4][2], accZ[4][2], accN1[4][2], accN2[4][2];
  #pragma unroll
  for (int rt = 0; rt < 4; ++rt)
    #pragma unroll
    for (int s = 0; s < 2; ++s) {
      #pragma unroll
      for (int q = 0; q < 4; ++q) { accR[rt][s][q] = 0.f; accZ[rt][s][q] = 0.f; accN1[rt][s][q] = 0.f; accN2[rt][s][q] = 0.f; }
    }

  // stage ALL 9 input chunks into BX, one barrier
  {
    const int gm = t >> 2, gb = t & 3, grow = rowBase + gm;
    const int i = gm & 7;
    #pragma unroll
    for (int ck = 0; ck < NCH; ++ck) {
      const int k0 = ck * 32 + gb * 8;
      s16x8 v = z8();
      if (k0 < 16)       v = *(const s16x8*)(xh + grow * 144 + k0);
      else if (k0 < 144) {
        if (i < 7) {
          const int ke = k0 - 16;
          v = *(const s16x8*)&As_e[(ke >> 5) * 2048 + swz_blk(gm, (ke & 31) >> 3)];
        }
      } else if (k0 >= 160) {
        v = *(const s16x8*)(xh + grow * 144 + 16 + (k0 - 160));
      }
      *(s16x8*)&BX[ck * 2048 + swz_blk(gm, gb)] = v;
    }
  }
  __syncthreads();

  // 9 MFMA rounds, no barriers
  #pragma unroll
  for (int ck = 0; ck < NCH; ++ck) {
    const ush* Wc = WT + ck * 16384;
    s16x8 af[4];
    #pragma unroll
    for (int rt = 0; rt < 4; ++rt)
      af[rt] = *(const s16x8*)&BX[ck * 2048 + swz_blk(rt * 16 + l15, quad)];
    if (ck < XCH) {
      #pragma unroll
      for (int s = 0; s < 2; ++s) {
        const int nb = w * 32 + s * 16 + l15;
        const s16x8 bR = *(const s16x8*)&Wc[swz_blk(0 * 128 + nb, quad)];
        const s16x8 bZ = *(const s16x8*)&Wc[swz_blk(1 * 128 + nb, quad)];
        const s16x8 bN = *(const s16x8*)&Wc[swz_blk(2 * 128 + nb, quad)];
        #pragma unroll
        for (int rt = 0; rt < 4; ++rt) {
          accR[rt][s]  = MFMA(af[rt], bR, accR[rt][s]);
          accZ[rt][s]  = MFMA(af[rt], bZ, accZ[rt][s]);
          accN1[rt][s] = MFMA(af[rt], bN, accN1[rt][s]);
        }
      }
    } else {
      #pragma unroll
      for (int s = 0; s < 2; ++s) {
        const int nb = w * 32 + s * 16 + l15;
        const s16x8 bR = *(const s16x8*)&Wc[swz_blk(0 * 128 + nb, quad)];
        const s16x8 bZ = *(const s16x8*)&Wc[swz_blk(1 * 128 + nb, quad)];
        const s16x8 bN = *(const s16x8*)&Wc[swz_blk(3 * 128 + nb, quad)];
        #pragma unroll
        for (int rt = 0; rt < 4; ++rt) {
          accR[rt][s]  = MFMA(af[rt], bR, accR[rt][s]);
          accZ[rt][s]  = MFMA(af[rt], bZ, accZ[rt][s]);
          accN2[rt][s] = MFMA(af[rt], bN, accN2[rt][s]);
        }
      }
    }
  }

  #pragma unroll
  for (int s = 0; s < 2; ++s) {
    const int hcol = w * 32 + s * 16 + l15;
    const float bR = bias[hcol], bZ = bias[128 + hcol], bN1 = bias[256 + hcol], bN2 = bias[384 + hcol];
    #pragma unroll
    for (int rt = 0; rt < 4; ++rt) {
      #pragma unroll
      for (int q = 0; q < 4; ++q) {
        const int r = rt * 16 + quad * 4 + q;
        const int row = rowBase + r;
        const float hp = u2f(xh[row * 144 + 16 + hcol]);
        const float rg = sigmoid_f(accR[rt][s][q] + bR);
        const float zg = sigmoid_f(accZ[rt][s][q] + bZ);
        const float nn = tanh_f(accN1[rt][s][q] + bN1 + rg * (accN2[rt][s][q] + bN2));
        xh[row * 144 + 16 + hcol] = f2u(nn + zg * (hp - nn));
      }
    }
  }
}

// per-block readout: esum from As_e (final edges), hsum from xh (final h)
DEV void sums_body(const ush* As_e, const ush* __restrict__ xh,
                   float* __restrict__ hsum, float* __restrict__ esum,
                   int G0, int rowBase, int t)
{
  #pragma unroll
  for (int ii = 0; ii < 4; ++ii) {
    const int p = t + ii * 256;
    const int gg = p >> 7, hh = p & 127;
    float es = 0.f;
    #pragma unroll
    for (int i = 0; i < 7; ++i) {
      const int slot = gg * 8 + i;
      es += u2f(As_e[(hh >> 5) * 2048 + swz_idx(slot, hh & 31)]);
    }
    float hs = 0.f;
    #pragma unroll
    for (int i = 0; i < 8; ++i)
      hs += u2f(xh[(rowBase + gg * 8 + i) * 144 + 16 + hh]);
    hsum[(G0 + gg) * 128 + hh] = hs;
    esum[(G0 + gg) * 128 + hh] = es;
  }
}

// ---------------------------------------------------------------------------
// One fused GN iteration: [Ee MLP | eh load] -> edge GRU -> node GRU [-> sums]
// LDS: As_e 16KB + BX 36KB = 52KB.
// ---------------------------------------------------------------------------
template<int FIRST, int LAST>
__global__ __launch_bounds__(256, 2) void gn_iter(
    ush* __restrict__ eh, ush* __restrict__ xh,
    const ush* __restrict__ WIHe, const ush* __restrict__ WTh,
    const float* __restrict__ biasM,
    const ush* __restrict__ WTu, const float* __restrict__ biasU,
    const ush* __restrict__ WBee1, const float* __restrict__ bEe1,
    const ush* __restrict__ WBee2, const float* __restrict__ bEe2,
    float* __restrict__ hsum, float* __restrict__ esum)
{
  __shared__ ush smem[26624];          // As_e [0,8192) | BX [8192,26624)
  ush* As_e = smem;
  ush* BX   = smem + 8192;
  const int t = threadIdx.x;
  const int G0 = blockIdx.x * 8, rowBase = blockIdx.x * 64;

  if (FIRST) {
    ee_body(As_e, BX, xh, WBee1, bEe1, WBee2, bEe2, G0, t);
  } else {
    const int gm = t >> 2, gb = t & 3;
    const int gg = gm >> 3, i = gm & 7;
    const ush* src = eh + (size_t)((G0 + gg) * 64 + i * 9 + 1) * 128;
    #pragma unroll
    for (int ck = 0; ck < 4; ++ck) {
      s16x8 v = z8();
      if (i < 7) v = *(const s16x8*)(src + ck * 32 + gb * 8);
      *(s16x8*)&As_e[ck * 2048 + swz_blk(gm, gb)] = v;
    }
  }
  __syncthreads();

  edge_core<LAST>(As_e, BX, eh, WIHe, WTh, biasM, xh, G0, t);
  __syncthreads();

  node_lds(As_e, BX, xh, WTu, biasU, rowBase, t);

  if (LAST) {
    __syncthreads();
    sums_body(As_e, xh, hsum, esum, G0, rowBase, t);
  }
}

// global GRU (h_prev = 0) fused with output head: 16 graphs per block.
__global__ __launch_bounds__(256) void gru_global_out(
    const float* __restrict__ hsum, const float* __restrict__ esum,
    const float* __restrict__ WT, const float* __restrict__ bias,
    const float* __restrict__ OW, const float* __restrict__ Ob,
    float* __restrict__ out)
{
  constexpr int KT = 384;
  __shared__ float4 ATl4[KT * 4];
  __shared__ float4 Bl4[16 * 128];
  __shared__ float gmat[16 * 128];
  __shared__ float red[16 * 4];
  float* ATl = (float*)ATl4;
  const int t = threadIdx.x;
  const int rowBase = blockIdx.x * 16;
  for (int idx = t; idx < KT * 16; idx += 256) {
    const int kc = idx >> 4, r = idx & 15, grow = rowBase + r;
    float v = 0.f;
    if (kc < 128)      v = hsum[grow * 128 + kc];
    else if (kc < 256) v = esum[grow * 128 + (kc - 128)];
    ATl[idx] = v;
  }
  const int c = t & 127, rh = t >> 7;
  float accR[8], accZ[8], accN1[8];
  #pragma unroll
  for (int rr = 0; rr < 8; ++rr) { accR[rr] = 0.f; accZ[rr] = 0.f; accN1[rr] = 0.f; }
  const float4* WT4 = (const float4*)WT;
  for (int ck = 0; ck < 16; ++ck) {
    __syncthreads();
    #pragma unroll
    for (int ii = 0; ii < 8; ++ii) { const int idx = t + ii * 256; Bl4[idx] = WT4[ck * 2048 + idx]; }
    __syncthreads();
    const int kb = ck * 16;
    #pragma unroll
    for (int kcl = 0; kcl < 16; ++kcl) {
      const float4 wv = Bl4[kcl * 128 + c];
      const float4 a0 = ATl4[(kb + kcl) * 4 + rh * 2];
      const float4 a1 = ATl4[(kb + kcl) * 4 + rh * 2 + 1];
      const float av[8] = {a0.x, a0.y, a0.z, a0.w, a1.x, a1.y, a1.z, a1.w};
      #pragma unroll
      for (int rr = 0; rr < 8; ++rr) {
        accR[rr]  += wv.x * av[rr];
        accZ[rr]  += wv.y * av[rr];
        accN1[rr] += wv.z * av[rr];
      }
    }
  }
  const float4 bb = ((const float4*)bias)[c];
  const float ow = OW[c];
  #pragma unroll
  for (int rr = 0; rr < 8; ++rr) {
    const float rg = sigmoid_f(accR[rr] + bb.x);
    const float zg = sigmoid_f(accZ[rr] + bb.y);
    const float nn = tanh_f(accN1[rr] + bb.z + rg * bb.w);
    gmat[(rh * 8 + rr) * 128 + c] = (1.f - zg) * nn * ow;
  }
  __syncthreads();
  if (t < 64) {
    const int r = t >> 2, part = t & 3;
    float s = 0.f;
    #pragma unroll
    for (int cc = 0; cc < 32; ++cc) s += gmat[r * 128 + part * 32 + cc];
    red[r * 4 + part] = s;
  }
  __syncthreads();
  if (t < 16) {
    const float s = red[t * 4] + red[t * 4 + 1] + red[t * 4 + 2] + red[t * 4 + 3];
    out[rowBase + t] = sigmoid_f(s + Ob[0]);
  }
}

// ---------------------------------------------------------------------------
extern "C" void kernel_launch(void* const* d_in, const int* in_sizes, int n_in,
                              void* d_out, int out_size, void* d_ws, size_t ws_size,
                              hipStream_t stream)
{
  (void)in_sizes; (void)n_in; (void)out_size; (void)ws_size;
  const float* towers = (const float*)d_in[0];
  const float* EnW1 = (const float*)d_in[1];
  const float* EnB1 = (const float*)d_in[2];
  const float* EnW2 = (const float*)d_in[3];
  const float* EnB2 = (const float*)d_in[4];
  const float* EeW1 = (const float*)d_in[5];
  const float* EeB1 = (const float*)d_in[6];
  const float* EeW2 = (const float*)d_in[7];
  const float* EeB2 = (const float*)d_in[8];
  const float* UWih = (const float*)d_in[9];
  const float* UWhh = (const float*)d_in[10];
  const float* UBih = (const float*)d_in[11];
  const float* UBhh = (const float*)d_in[12];
  const float* MWih = (const float*)d_in[13];
  const float* MWhh = (const float*)d_in[14];
  const float* MBih = (const float*)d_in[15];
  const float* MBhh = (const float*)d_in[16];
  const float* GWih = (const float*)d_in[17];
  const float* GWhh = (const float*)d_in[18];
  const float* GBih = (const float*)d_in[19];
  const float* GBhh = (const float*)d_in[20];
  const float* OW   = (const float*)d_in[21];
  const float* Ob   = (const float*)d_in[22];

  char* ws = (char*)d_ws;
  size_t off = 0;
  auto take = [&](size_t b) { void* p = ws + off; off = (off + b + 255) & ~(size_t)255; return p; };
  ush*   xh     = (ush*)take((size_t)32768 * 144 * 2);
  ush*   eh     = (ush*)take((size_t)262144 * 128 * 2);
  float* hsum   = (float*)take((size_t)4096 * 128 * 4);
  float* esum   = (float*)take((size_t)4096 * 128 * 4);
  ush*   WIHe   = (ush*)take((size_t)9 * 384 * 32 * 2);
  ush*   WTh    = (ush*)take((size_t)4 * 384 * 32 * 2);
  ush*   WTu    = (ush*)take((size_t)9 * 512 * 32 * 2);
  ush*   WBen1  = (ush*)take((size_t)128 * 32 * 2);
  ush*   WBen2  = (ush*)take((size_t)4 * 128 * 32 * 2);
  ush*   WBee1  = (ush*)take((size_t)128 * 32 * 2);
  ush*   WBee2  = (ush*)take((size_t)4 * 128 * 32 * 2);
  float* biasM  = (float*)take(512 * 4);
  float* biasU  = (float*)take(512 * 4);
  float* WT_G   = (float*)take((size_t)384 * 512 * 4);
  float* biasG  = (float*)take(512 * 4);

  prep_all<<<4182, 256, 0, stream>>>(
      towers, MWih, MWhh, UWih, UWhh, EnW1, EnW2, EeW1, EeW2,
      MBih, MBhh, UBih, UBhh, GWih, GWhh, GBih, GBhh,
      xh, WIHe, WTh, WTu, WBen1, WBen2, WBee1, WBee2,
      biasM, biasU, WT_G, biasG);

  // node encoder
  enc_en<<<512, 256, 0, stream>>>(xh, WBen1, EnB1, WBen2, EnB2);

  // fused iterations: [Ee | eh] -> edge GRU -> node GRU [-> sums]
  gn_iter<1, 0><<<512, 256, 0, stream>>>(eh, xh, WIHe, WTh, biasM, WTu, biasU,
                                         WBee1, EeB1, WBee2, EeB2, hsum, esum);
  gn_iter<0, 0><<<512, 256, 0, stream>>>(eh, xh, WIHe, WTh, biasM, WTu, biasU,
                                         WBee1, EeB1, WBee2, EeB2, hsum, esum);
  gn_iter<0, 1><<<512, 256, 0, stream>>>(eh, xh, WIHe, WTh, biasM, WTu, biasU,
                                         WBee1, EeB1, WBee2, EeB2, hsum, esum);

  gru_global_out<<<256, 256, 0, stream>>>(hsum, esum, WT_G, biasG, OW, Ob, (float*)d_out);
}